// Round 18
// baseline (1981.334 us; speedup 1.0000x reference)
//
#include <hip/hip_runtime.h>
#include <hip/hip_bf16.h>
#include <float.h>

#define NPTS 16384
#define KK 20
#define COUT 3
#define SURV_CAP 256
#define RQSLOTS 256

typedef float f4 __attribute__((ext_vector_type(4)));
typedef float f32x4 __attribute__((ext_vector_type(4)));
typedef short bh8 __attribute__((ext_vector_type(8)));   // 8 bf16 in 4 VGPRs

// ---------------- sorted top-20 insert, values only ----------------
__device__ __forceinline__ void ins20(float (&td)[KK], float &kmax, float nd) {
  float cd = nd;
#pragma unroll
  for (int j = 0; j < KK; ++j) {
    float t0 = td[j];
    bool lt = cd < t0;
    td[j] = lt ? cd : t0;
    cd = lt ? t0 : cd;
  }
  kmax = td[KK - 1];
}

// ---------------- sorted top-4 insert, values only ----------------
__device__ __forceinline__ void ins4(float (&td)[4], float &kmax, float nd) {
  float cd = nd;
#pragma unroll
  for (int j = 0; j < 4; ++j) {
    float t0 = td[j];
    bool lt = cd < t0;
    td[j] = lt ? cd : t0;
    cd = lt ? t0 : cd;
  }
  kmax = td[3];
}

// ---------------- sorted top-20 insert, (value, index) ----------------
__device__ __forceinline__ void ins20p(float (&td)[KK], int (&ti)[KK],
                                       float &kmax, float nd, int ni) {
  float cd = nd; int ci = ni;
#pragma unroll
  for (int j = 0; j < KK; ++j) {
    float t0 = td[j]; int t1 = ti[j];
    bool lt = cd < t0;
    td[j] = lt ? cd : t0;  ti[j] = lt ? ci : t1;
    cd = lt ? t0 : cd;     ci = lt ? t1 : ci;
  }
  kmax = td[KK - 1];
}

// ---------------- row squared norms (stage-1 / C=3 path) ----------------
template<int C>
__global__ void norms_kernel(const float* __restrict__ X, int ldx, float* __restrict__ vn) {
  int i = blockIdx.x * 256 + threadIdx.x;
  if (i >= NPTS) return;
  const float* row = X + (size_t)i * ldx;
  float s = 0.f;
#pragma unroll
  for (int c = 0; c < C; ++c) s = fmaf(row[c], row[c], s);
  vn[i] = s;
}

// ---------------- deterministic column mean over 64 dims ----------------
__global__ __launch_bounds__(256)
void mean64_kernel(const float* __restrict__ X, int ldx, float* __restrict__ mean) {
  __shared__ float p[256];
  const int d = blockIdx.x, t = threadIdx.x;
  float s = 0.f;
  for (int r = t; r < NPTS; r += 256) s += X[(size_t)r * ldx + d];
  p[t] = s;
  __syncthreads();
  for (int o = 128; o > 0; o >>= 1) { if (t < o) p[t] += p[t + o]; __syncthreads(); }
  if (t == 0) mean[d] = p[0] * (1.0f / NPTS);
}

// ---------------- center + fp32 copy + bf16 copy + vn + sn  (64-dim slice) --------
__global__ __launch_bounds__(256)
void xc_kernel(const float* __restrict__ X, int ldx, const float* __restrict__ mean,
               float* __restrict__ Xc, short* __restrict__ Xbf,
               float* __restrict__ vn, float* __restrict__ sn) {
  __shared__ float msh[64];
  const int t = threadIdx.x;
  if (t < 64) msh[t] = mean[t];
  __syncthreads();
  const int row = blockIdx.x * 32 + (t >> 3), sub = t & 7;
  f4 a = *(const f4*)&X[(size_t)row * ldx + sub * 8];
  f4 b = *(const f4*)&X[(size_t)row * ldx + sub * 8 + 4];
#pragma unroll
  for (int e = 0; e < 4; ++e) { a[e] -= msh[sub * 8 + e]; b[e] -= msh[sub * 8 + 4 + e]; }
  *(f4*)&Xc[(size_t)row * 64 + sub * 8] = a;
  *(f4*)&Xc[(size_t)row * 64 + sub * 8 + 4] = b;
  bh8 o;
#pragma unroll
  for (int e = 0; e < 4; ++e) {
    __hip_bfloat16 ha = __float2bfloat16(a[e]);
    __hip_bfloat16 hb = __float2bfloat16(b[e]);
    o[e] = *reinterpret_cast<short*>(&ha);
    o[4 + e] = *reinterpret_cast<short*>(&hb);
  }
  *(bh8*)&Xbf[(size_t)row * 64 + sub * 8] = o;
  float s = a[0]*a[0] + a[1]*a[1] + a[2]*a[2] + a[3]*a[3]
          + b[0]*b[0] + b[1]*b[1] + b[2]*b[2] + b[3]*b[3];
  s += __shfl_xor(s, 1);
  s += __shfl_xor(s, 2);
  s += __shfl_xor(s, 4);
  if (sub == 0) { vn[row] = s; sn[row] = sqrtf(s); }
}

// ---------------- phase S v4: tiled sampler -> per-thread top-4 lists -------------
template<int C>
__global__ __launch_bounds__(256, 2)
void sampleTv4_kernel(const float* __restrict__ X, const float* __restrict__ vn,
                      float* __restrict__ plist) {
  __shared__ __align__(16) float Qs[C * 64];     // dim-major [d][q]
  __shared__ __align__(16) float Cs[C * 132];    // dim-major [d][r], pad->132
  __shared__ float cn[128];
  const int t = threadIdx.x;
  const int qb = blockIdx.x * 64;
  const int tb = blockIdx.y ? 11 : 0;
  const int nt = blockIdx.y ? 10 : 11;           // 21 tiles total

  if constexpr (C == 64) {
#pragma unroll
    for (int u = 0; u < 4; ++u) {
      int idx = u * 256 + t;
      int q = idx & 63, dg = idx >> 6;
      f4 v = *(const f4*)&X[(size_t)(qb + q) * C + dg * 4];
#pragma unroll
      for (int e = 0; e < 4; ++e) Qs[(dg * 4 + e) * 64 + q] = v[e];
    }
  } else {
    for (int idx = t; idx < C * 64; idx += 256) {
      int q = idx & 63, d = idx >> 6;
      Qs[d * 64 + q] = X[(size_t)(qb + q) * C + d];
    }
  }

  const int tq = t & 15, tc = t >> 4;
  const int q0 = tq * 4, c0 = tc * 8;

  float l4[4][4]; float km[4];
#pragma unroll
  for (int i = 0; i < 4; ++i) {
    km[i] = FLT_MAX;
#pragma unroll
    for (int k = 0; k < 4; ++k) l4[i][k] = FLT_MAX;
  }

  for (int tt = 0; tt < nt; ++tt) {
    const int base = (tb + tt) * 128;
    __syncthreads();
    if constexpr (C == 64) {
#pragma unroll
      for (int u = 0; u < 8; ++u) {
        int idx = u * 256 + t;
        int r = idx & 127, dg = idx >> 7;
        f4 v = *(const f4*)&X[(size_t)((base + r) * 6) * C + dg * 4];
#pragma unroll
        for (int e = 0; e < 4; ++e) Cs[(dg * 4 + e) * 132 + r] = v[e];
      }
    } else {
      for (int idx = t; idx < C * 128; idx += 256) {
        int r = idx & 127, d = idx >> 7;
        Cs[d * 132 + r] = X[(size_t)((base + r) * 6) * C + d];
      }
    }
    if (t < 128) cn[t] = vn[(base + t) * 6];
    __syncthreads();

    float acc[4][8];
#pragma unroll
    for (int i = 0; i < 4; ++i)
#pragma unroll
      for (int j = 0; j < 8; ++j) acc[i][j] = 0.f;

#pragma unroll 4
    for (int d = 0; d < C; ++d) {
      f4 qa = *(const f4*)&Qs[d * 64 + q0];
      f4 ca = *(const f4*)&Cs[d * 132 + c0];
      f4 cb = *(const f4*)&Cs[d * 132 + c0 + 4];
      float cr[8] = {ca[0], ca[1], ca[2], ca[3], cb[0], cb[1], cb[2], cb[3]};
#pragma unroll
      for (int i = 0; i < 4; ++i)
#pragma unroll
        for (int j = 0; j < 8; ++j)
          acc[i][j] = fmaf(qa[i], cr[j], acc[i][j]);
    }

#pragma unroll
    for (int j = 0; j < 8; ++j) {
      float cv = cn[c0 + j];
#pragma unroll
      for (int i = 0; i < 4; ++i) {
        float sv = fmaf(-2.f, acc[i][j], cv);
        if (sv < km[i]) ins4(l4[i], km[i], sv);
      }
    }
  }

#pragma unroll
  for (int i = 0; i < 4; ++i) {
    size_t off = (((size_t)blockIdx.y * NPTS + (qb + q0 + i)) * 16 + tc) * 4;
    f4 v = {l4[i][0], l4[i][1], l4[i][2], l4[i][3]};
    *(f4*)&plist[off] = v;
  }
}

// ---------------- merge plist -> T; zero cnt/redoCnt ----------------
__global__ __launch_bounds__(256)
void mergeT_kernel(const float* __restrict__ plist, float* __restrict__ T,
                   unsigned* __restrict__ cnt, unsigned* __restrict__ redoCnt) {
  const int q = blockIdx.x * 256 + threadIdx.x;
  float td[KK];
#pragma unroll
  for (int j = 0; j < KK; ++j) td[j] = FLT_MAX;
  float km = FLT_MAX;
  for (int s = 0; s < 2; ++s) {
    const float* p = &plist[((size_t)s * NPTS + q) * 64];
    for (int z = 0; z < 64; ++z) {
      float v = p[z];
      if (v < km) ins20(td, km, v);
    }
  }
  T[q] = td[KK - 1] + 1e-4f * (fabsf(td[KK - 1]) + 1.0f);
  cnt[q] = 0u;
  if (q == 0) *redoCnt = 0u;
}

// ---------------- phase F (C=3): register-query filter + LDS survivor aggregation --
// CAPB=28 keeps LDS ~37 KB -> 4 blocks/CU. Overflow falls back to global append.
__global__ __launch_bounds__(256, 4)
void knn_filter3_kernel(const float* __restrict__ X, const float* __restrict__ vn,
                        const float* __restrict__ T,
                        float* __restrict__ survd, int* __restrict__ survi,
                        unsigned* __restrict__ cnt) {
  constexpr int CAPB = 28;
  __shared__ __align__(16) f4 CsV[512];            // (x,y,z,vn) packed, 8 KB
  __shared__ float Tsl[128];
  __shared__ unsigned scnt[128];
  __shared__ float sbD[128 * CAPB];
  __shared__ int   sbI[128 * CAPB];

  const int t = threadIdx.x;
  const int qb = blockIdx.x * 128;
  const int cbase = blockIdx.y * 2048;
  if (t < 128) { Tsl[t] = T[qb + t]; scnt[t] = 0u; }
  __syncthreads();

  const int tq = t & 15, tc = t >> 4;
  const int q0 = tq * 8, c0loc = tc * 8;

  float qx[8], qy[8], qz[8], tr[8];
#pragma unroll
  for (int i = 0; i < 8; ++i) {
    const float* qr = &X[(size_t)(qb + q0 + i) * 3];
    qx[i] = qr[0]; qy[i] = qr[1]; qz[i] = qr[2];
    tr[i] = Tsl[q0 + i];
  }

  for (int rd = 0; rd < 4; ++rd) {
    const int cb = cbase + rd * 512;
    __syncthreads();   // prior round's CsV reads done
#pragma unroll
    for (int u = 0; u < 2; ++u) {
      int idx = u * 256 + t;
      int c = cb + idx;
      const float* cr = &X[(size_t)c * 3];
      f4 v = {cr[0], cr[1], cr[2], vn[c]};
      CsV[idx] = v;
    }
    __syncthreads();

#pragma unroll
    for (int sub = 0; sub < 4; ++sub) {
      const int cl0 = sub * 128 + c0loc;
#pragma unroll
      for (int j = 0; j < 8; ++j) {
        f4 cv = CsV[cl0 + j];
        const int cglob = cb + cl0 + j;
#pragma unroll
        for (int i = 0; i < 8; ++i) {
          float d0 = fmaf(qx[i], cv[0], fmaf(qy[i], cv[1], qz[i] * cv[2]));
          float sv = fmaf(-2.f, d0, cv[3]);
          if (sv <= tr[i]) {
            unsigned p = atomicAdd(&scnt[q0 + i], 1u);
            if (p < CAPB) {
              sbD[(q0 + i) * CAPB + p] = sv;
              sbI[(q0 + i) * CAPB + p] = cglob;
            } else {  // rare fallback: direct global append
              unsigned gp = atomicAdd(&cnt[qb + q0 + i], 1u);
              if (gp < SURV_CAP) {
                survd[(size_t)(qb + q0 + i) * SURV_CAP + gp] = sv;
                survi[(size_t)(qb + q0 + i) * SURV_CAP + gp] = cglob;
              }
            }
          }
        }
      }
    }
  }

  __syncthreads();
  if (t < 128) {
    unsigned n = scnt[t]; if (n > CAPB) n = CAPB;
    if (n) {
      unsigned base = atomicAdd(&cnt[qb + t], n);
      for (unsigned i = 0; i < n; ++i) {
        unsigned p = base + i;
        if (p < SURV_CAP) {
          survd[(size_t)(qb + t) * SURV_CAP + p] = sbD[t * CAPB + i];
          survi[(size_t)(qb + t) * SURV_CAP + p] = sbI[t * CAPB + i];
        }
      }
    }
  }
}

// ---------------- phase F (C=64): MFMA bf16 filter, 2 cand tiles per block --------
// grid (128, 64). Q tile + Tq/snq/scnt staged once; Cs restaged per tile.
__global__ __launch_bounds__(256, 2)
void knn_filter64_mfma(const short* __restrict__ Xbf, const float* __restrict__ vn,
                       const float* __restrict__ sn, const float* __restrict__ T,
                       int* __restrict__ survi, unsigned* __restrict__ cnt) {
  __shared__ __align__(16) short Qs[128 * 64];
  __shared__ __align__(16) short Cs[128 * 64];
  __shared__ float vnc[128], snq[128], snc[128], Tq[128];
  __shared__ unsigned scnt[128];
  __shared__ int sbI[128 * 8];

  const int t = threadIdx.x;
  const int qb = blockIdx.x * 128;

#pragma unroll
  for (int p = 0; p < 4; ++p) {
    int idx = p * 256 + t;
    int row = idx >> 3, sl = idx & 7;
    int slq = sl ^ (row & 7);
    *(bh8*)&Qs[row * 64 + slq * 8] = *(const bh8*)&Xbf[(size_t)(qb + row) * 64 + sl * 8];
  }
  if (t < 128) { Tq[t] = T[qb + t]; snq[t] = sn[qb + t]; scnt[t] = 0u; }

  const int w = t >> 6, l = t & 63;
  const int qsub = (w >> 1) * 64, csub = (w & 1) * 64;
  const int lr = l & 15, lh = l >> 4;

  for (int cc = 0; cc < 2; ++cc) {
    const int cb = blockIdx.y * 256 + cc * 128;
    __syncthreads();   // Q/T staged (cc=0); prior tile's epilogue reads done (cc=1)
#pragma unroll
    for (int p = 0; p < 4; ++p) {
      int idx = p * 256 + t;
      int row = idx >> 3, sl = idx & 7;
      int slq = sl ^ (row & 7);
      *(bh8*)&Cs[row * 64 + slq * 8] = *(const bh8*)&Xbf[(size_t)(cb + row) * 64 + sl * 8];
    }
    if (t >= 128) { vnc[t - 128] = vn[cb + t - 128]; snc[t - 128] = sn[cb + t - 128]; }
    __syncthreads();

    f32x4 acc[4][4];
#pragma unroll
    for (int i = 0; i < 4; ++i)
#pragma unroll
      for (int j = 0; j < 4; ++j) acc[i][j] = f32x4{0.f, 0.f, 0.f, 0.f};

#pragma unroll
    for (int kk = 0; kk < 2; ++kk) {
      const int sl = kk * 4 + lh;
      bh8 af[4], bf[4];
#pragma unroll
      for (int i = 0; i < 4; ++i) {
        int qr = qsub + i * 16 + lr;
        af[i] = *(const bh8*)&Qs[qr * 64 + (sl ^ (qr & 7)) * 8];
        int cr = csub + i * 16 + lr;
        bf[i] = *(const bh8*)&Cs[cr * 64 + (sl ^ (cr & 7)) * 8];
      }
#pragma unroll
      for (int i = 0; i < 4; ++i)
#pragma unroll
        for (int j = 0; j < 4; ++j)
          acc[i][j] = __builtin_amdgcn_mfma_f32_16x16x32_bf16(af[i], bf[j], acc[i][j], 0, 0, 0);
    }

#pragma unroll
    for (int i = 0; i < 4; ++i) {
#pragma unroll
      for (int r = 0; r < 4; ++r) {
        const int ql = qsub + i * 16 + lh * 4 + r;
        const float tcut = Tq[ql];
        const float sq = snq[ql];
        const int q = qb + ql;
#pragma unroll
        for (int j = 0; j < 4; ++j) {
          const int cl = csub + j * 16 + lr;
          float s = fmaf(-2.f, acc[i][j][r], vnc[cl]);
          float margin = 0.0082f * sq * snc[cl] + 1e-6f;
          if (s <= tcut + margin) {
            unsigned p = atomicAdd(&scnt[ql], 1u);
            if (p < 8u) sbI[ql * 8 + p] = cb + cl;
            else {  // rare fallback
              unsigned gp = atomicAdd(&cnt[q], 1u);
              if (gp < SURV_CAP) survi[(size_t)q * SURV_CAP + gp] = cb + cl;
            }
          }
        }
      }
    }
  }

  __syncthreads();
  if (t < 128) {
    unsigned n = scnt[t]; if (n > 8u) n = 8u;
    if (n) {
      unsigned base = atomicAdd(&cnt[qb + t], n);
      for (unsigned i = 0; i < n; ++i) {
        unsigned p = base + i;
        if (p < SURV_CAP) survi[(size_t)(qb + t) * SURV_CAP + p] = sbI[t * 8 + i];
      }
    }
  }
}

// ---------------- exact fp32 recompute of survivor distances (C=64 path) ----------
template<int C>
__global__ __launch_bounds__(256, 2)
void exact_kernel(const float* __restrict__ X, int ldx, const float* __restrict__ vn,
                  const unsigned* __restrict__ cnt, const int* __restrict__ survi,
                  float* __restrict__ survd) {
  __shared__ float qsh[C];
  const int q = blockIdx.x;
  const int t = threadIdx.x;
  if (t < C) qsh[t] = X[(size_t)q * ldx + t];
  __syncthreads();
  unsigned n = cnt[q];
  if (n > SURV_CAP) n = SURV_CAP;
  if (t < n) {
    const int c = survi[(size_t)q * SURV_CAP + t];
    const float* crow = X + (size_t)c * ldx;
    float d0 = 0.f, d1 = 0.f, d2 = 0.f, d3 = 0.f;
#pragma unroll
    for (int s = 0; s < C / 4; ++s) {
      f4 cv = *(const f4*)&crow[s * 4];
      d0 = fmaf(cv[0], qsh[s * 4 + 0], d0);
      d1 = fmaf(cv[1], qsh[s * 4 + 1], d1);
      d2 = fmaf(cv[2], qsh[s * 4 + 2], d2);
      d3 = fmaf(cv[3], qsh[s * 4 + 3], d3);
    }
    survd[(size_t)q * SURV_CAP + t] = fmaf(-2.f, (d0 + d1) + (d2 + d3), vn[c]);
  }
}

// ---------------- phase Sel: exact top-20 among survivors (overflow -> redo list) --
__global__ __launch_bounds__(256, 2)
void select_kernel(const float* __restrict__ survd, const int* __restrict__ survi,
                   const unsigned* __restrict__ cnt, int* __restrict__ ind,
                   unsigned* __restrict__ redoCnt, int* __restrict__ redoList) {
  const int q = blockIdx.x * 256 + threadIdx.x;
  const unsigned n = cnt[q];
  if (n > SURV_CAP) {   // dense-cluster overflow: defer to parallel redo kernels
    unsigned p = atomicAdd(redoCnt, 1u);
    redoList[p] = q;
    return;
  }
  float td[KK]; int ti[KK];
#pragma unroll
  for (int j = 0; j < KK; ++j) { td[j] = FLT_MAX; ti[j] = 0; }
  float kmax = FLT_MAX;
  for (unsigned i = 0; i < n; ++i) {
    float d = survd[(size_t)q * SURV_CAP + i];
    if (d < kmax) ins20p(td, ti, kmax, d, survi[(size_t)q * SURV_CAP + i]);
  }
#pragma unroll
  for (int j = 0; j < KK; ++j) ind[q * KK + j] = ti[j];
}

// ---------------- redo pass 1: 32 blocks per query, each scans a 512-cand slab ----
template<int C>
__global__ __launch_bounds__(256, 2)
void knn_redo_p1(const float* __restrict__ X, int ldx, const float* __restrict__ vn,
                 const int* __restrict__ redoList, const unsigned* __restrict__ redoCnt,
                 float* __restrict__ rpd, int* __restrict__ rpi) {
  __shared__ float lds_d[256 * KK];
  __shared__ int   lds_i[256 * KK];
  const int t = threadIdx.x;
  const unsigned n = *redoCnt;
  const unsigned e = blockIdx.x >> 5;
  const int part = blockIdx.x & 31;
  if (e >= n || e >= (unsigned)RQSLOTS) return;
  const int q = redoList[e];
  float qreg[C];
#pragma unroll
  for (int d = 0; d < C; ++d) qreg[d] = X[(size_t)q * ldx + d];
  float td[KK]; int ti[KK];
#pragma unroll
  for (int j = 0; j < KK; ++j) { td[j] = FLT_MAX; ti[j] = 0; }
  float kmax = FLT_MAX;
  const int cbase = part * 512;
#pragma unroll
  for (int u = 0; u < 2; ++u) {
    const int c = cbase + u * 256 + t;
    const float* crow = X + (size_t)c * ldx;
    float d0 = 0.f;
    if constexpr (C >= 4) {
      float d1 = 0.f, d2 = 0.f, d3 = 0.f;
#pragma unroll
      for (int s = 0; s < C / 4; ++s) {
        f4 cv = *(const f4*)&crow[s * 4];
        d0 = fmaf(cv[0], qreg[s * 4 + 0], d0);
        d1 = fmaf(cv[1], qreg[s * 4 + 1], d1);
        d2 = fmaf(cv[2], qreg[s * 4 + 2], d2);
        d3 = fmaf(cv[3], qreg[s * 4 + 3], d3);
      }
      d0 = (d0 + d1) + (d2 + d3);
    } else {
#pragma unroll
      for (int d = 0; d < C; ++d) d0 = fmaf(crow[d], qreg[d], d0);
    }
    float sv = fmaf(-2.f, d0, vn[c]);
    if (sv < kmax) ins20p(td, ti, kmax, sv, c);
  }
#pragma unroll
  for (int j = 0; j < KK; ++j) { lds_d[t * KK + j] = td[j]; lds_i[t * KK + j] = ti[j]; }
  __syncthreads();
  // tree merge 256 -> 64 -> 16 -> 4 -> 1 (early-break keeps sparse lists cheap)
#pragma unroll
  for (int G = 1; G <= 64; G *= 4) {
    const int nth = (G == 64) ? 1 : (G == 16) ? 4 : (G == 4) ? 16 : 64;
    if (t < nth) {
      float md[KK]; int mi[KK];
#pragma unroll
      for (int j = 0; j < KK; ++j) { md[j] = FLT_MAX; mi[j] = 0; }
      float km = FLT_MAX;
      for (int s = 0; s < 4; ++s) {
        int base = ((t * 4 + s) * G) * KK;
        for (int j = 0; j < KK; ++j) {
          float v = lds_d[base + j];
          if (v < km) ins20p(md, mi, km, v, lds_i[base + j]);
          else break;
        }
      }
      int obase = (t * 4 * G) * KK;
#pragma unroll
      for (int j = 0; j < KK; ++j) { lds_d[obase + j] = md[j]; lds_i[obase + j] = mi[j]; }
    }
    __syncthreads();
  }
  if (t == 0) {
    size_t off = ((size_t)e * 32 + part) * KK;
#pragma unroll
    for (int j = 0; j < KK; ++j) { rpd[off + j] = lds_d[j]; rpi[off + j] = lds_i[j]; }
  }
}

// ---------------- redo pass 2: one thread per query merges its 32 sorted lists ----
__global__ __launch_bounds__(256)
void knn_redo_p2(const int* __restrict__ redoList, const unsigned* __restrict__ redoCnt,
                 const float* __restrict__ rpd, const int* __restrict__ rpi,
                 int* __restrict__ ind) {
  const unsigned e = blockIdx.x * 256 + threadIdx.x;
  const unsigned n = *redoCnt;
  if (e >= n || e >= (unsigned)RQSLOTS) return;
  const int q = redoList[e];
  float td[KK]; int ti[KK];
#pragma unroll
  for (int j = 0; j < KK; ++j) { td[j] = FLT_MAX; ti[j] = 0; }
  float kmax = FLT_MAX;
  for (int p = 0; p < 32; ++p) {
    const float* dd = &rpd[((size_t)e * 32 + p) * KK];
    const int* ii = &rpi[((size_t)e * 32 + p) * KK];
    for (int j = 0; j < KK; ++j) {
      float v = dd[j];
      if (v < kmax) ins20p(td, ti, kmax, v, ii[j]);
      else break;   // lists sorted ascending
    }
  }
#pragma unroll
  for (int j = 0; j < KK; ++j) ind[q * KK + j] = ti[j];
}

// ---------------- redo fallback: whole-scan per block for e >= RQSLOTS (rare) ------
template<int C>
__global__ __launch_bounds__(256, 2)
void knn_redo_kernel(const float* __restrict__ X, int ldx, const float* __restrict__ vn,
                     const int* __restrict__ redoList, const unsigned* __restrict__ redoCnt,
                     int* __restrict__ ind, unsigned ebase) {
  __shared__ float lds_d[256 * KK];
  __shared__ int   lds_i[256 * KK];
  const int t = threadIdx.x;
  const unsigned n = *redoCnt;
  for (unsigned e = ebase + blockIdx.x; e < n; e += gridDim.x) {
    const int q = redoList[e];
    float qreg[C];
#pragma unroll
    for (int d = 0; d < C; ++d) qreg[d] = X[(size_t)q * ldx + d];
    float td[KK]; int ti[KK];
#pragma unroll
    for (int j = 0; j < KK; ++j) { td[j] = FLT_MAX; ti[j] = 0; }
    float kmax = FLT_MAX;
    for (int c = t; c < NPTS; c += 256) {
      const float* crow = X + (size_t)c * ldx;
      float d0 = 0.f;
      if constexpr (C >= 4) {
        float d1 = 0.f, d2 = 0.f, d3 = 0.f;
#pragma unroll
        for (int s = 0; s < C / 4; ++s) {
          f4 cv = *(const f4*)&crow[s * 4];
          d0 = fmaf(cv[0], qreg[s * 4 + 0], d0);
          d1 = fmaf(cv[1], qreg[s * 4 + 1], d1);
          d2 = fmaf(cv[2], qreg[s * 4 + 2], d2);
          d3 = fmaf(cv[3], qreg[s * 4 + 3], d3);
        }
        d0 = (d0 + d1) + (d2 + d3);
      } else {
#pragma unroll
        for (int d = 0; d < C; ++d) d0 = fmaf(crow[d], qreg[d], d0);
      }
      float sv = fmaf(-2.f, d0, vn[c]);
      if (sv < kmax) ins20p(td, ti, kmax, sv, c);
    }
#pragma unroll
    for (int j = 0; j < KK; ++j) { lds_d[t * KK + j] = td[j]; lds_i[t * KK + j] = ti[j]; }
    __syncthreads();
#pragma unroll
    for (int G = 1; G <= 64; G *= 4) {
      const int nth = (G == 64) ? 1 : (G == 16) ? 4 : (G == 4) ? 16 : 64;
      if (t < nth) {
        float md[KK]; int mi[KK];
#pragma unroll
        for (int j = 0; j < KK; ++j) { md[j] = FLT_MAX; mi[j] = 0; }
        float km = FLT_MAX;
        for (int s = 0; s < 4; ++s) {
          int base = ((t * 4 + s) * G) * KK;
          for (int j = 0; j < KK; ++j) {
            float v = lds_d[base + j];
            if (v < km) ins20p(md, mi, km, v, lds_i[base + j]);
            else break;
          }
        }
        int obase = (t * 4 * G) * KK;
#pragma unroll
        for (int j = 0; j < KK; ++j) { lds_d[obase + j] = md[j]; lds_i[obase + j] = mi[j]; }
      }
      __syncthreads();
    }
    if (t == 0) {
#pragma unroll
      for (int j = 0; j < KK; ++j) ind[q * KK + j] = lds_i[j];
    }
    __syncthreads();
  }
}

// ---------------- UB precompute: U = x@W1_top, B = x@(W1_bot - W1_top) ------------
template<int CIN>
__global__ __launch_bounds__(256, 2)
void ub_kernel(const float* __restrict__ X, int ldx, const float* __restrict__ W1,
               float* __restrict__ UB) {
  __shared__ __align__(16) float Ws[2 * CIN * 64];
  __shared__ __align__(16) float Xs[32][(CIN == 3) ? 4 : CIN];
  const int t = threadIdx.x;
  for (int idx = t; idx < 2 * CIN * 64; idx += 256) Ws[idx] = W1[idx];
  const int pb = blockIdx.x * 32;
  if constexpr (CIN == 64) {
    int r = t >> 3, g = t & 7;
    f4 a = *(const f4*)&X[(size_t)(pb + r) * ldx + g * 8];
    f4 b = *(const f4*)&X[(size_t)(pb + r) * ldx + g * 8 + 4];
    *(f4*)&Xs[r][g * 8] = a;
    *(f4*)&Xs[r][g * 8 + 4] = b;
  } else {
    if (t < 32 * CIN) {
      int r = t / CIN, d = t - r * CIN;
      Xs[r][d] = X[(size_t)(pb + r) * ldx + d];
    }
  }
  __syncthreads();
  const int p = t >> 3, c0 = (t & 7) * 8;
  float u[8], v[8];
#pragma unroll
  for (int e = 0; e < 8; ++e) { u[e] = 0.f; v[e] = 0.f; }
#pragma unroll 4
  for (int k = 0; k < CIN; ++k) {
    float xv = Xs[p][k];
    f4 wt0 = *(const f4*)&Ws[k * 64 + c0];
    f4 wt1 = *(const f4*)&Ws[k * 64 + c0 + 4];
    f4 wb0 = *(const f4*)&Ws[(CIN + k) * 64 + c0];
    f4 wb1 = *(const f4*)&Ws[(CIN + k) * 64 + c0 + 4];
#pragma unroll
    for (int e = 0; e < 4; ++e) {
      u[e]     = fmaf(xv, wt0[e], u[e]);
      u[4 + e] = fmaf(xv, wt1[e], u[4 + e]);
      v[e]     = fmaf(xv, wb0[e], v[e]);
      v[4 + e] = fmaf(xv, wb1[e], v[4 + e]);
    }
  }
  float* o = &UB[(size_t)(pb + p) * 128];
  f4 a0 = {u[0], u[1], u[2], u[3]}, a1 = {u[4], u[5], u[6], u[7]};
  f4 b0 = {v[0] - u[0], v[1] - u[1], v[2] - u[2], v[3] - u[3]};
  f4 b1 = {v[4] - u[4], v[5] - u[5], v[6] - u[6], v[7] - u[7]};
  *(f4*)&o[c0] = a0;       *(f4*)&o[c0 + 4] = a1;
  *(f4*)&o[64 + c0] = b0;  *(f4*)&o[64 + c0 + 4] = b1;
}

// ---------------- edgeconv TWO-layer: h1 = prelu(U[nb]+B[i]); out = max prelu(h1@W2)
__global__ __launch_bounds__(256, 3)
void edgeconv2_kernel(const float* __restrict__ UB, const int* __restrict__ ind,
                      const float* __restrict__ W2, const float* __restrict__ p1p,
                      const float* __restrict__ p2p,
                      float* __restrict__ Y, int ldy) {
  __shared__ __align__(16) float W2s[64 * 64];     // 16 KB
  __shared__ __align__(16) float h1[4][64 * 32];   // 32 KB, [c][kslot]
  __shared__ float Bs[4][64];
  __shared__ int nbs[4][KK];
  const int t = threadIdx.x;
  const int w = t >> 6, l = t & 63;
  const float a1 = *p1p, a2 = *p2p;
  const int i = blockIdx.x * 4 + w;
  for (int idx = t; idx < 64 * 64; idx += 256) W2s[idx] = W2[idx];
  if (l < 16) *(f4*)&Bs[w][l * 4] = *(const f4*)&UB[(size_t)i * 128 + 64 + l * 4];
  if (l < KK) nbs[w][l] = ind[i * KK + l];
  __syncthreads();

  {  // build h1 for this warp's point: lane -> (kslot, channel half)
    const int kslot = l >> 1, ch0 = (l & 1) * 32;
    if (kslot < KK) {
      const int nb = nbs[w][kslot];
      const float* ur = &UB[(size_t)nb * 128 + ch0];
#pragma unroll
      for (int g = 0; g < 8; ++g) {
        f4 uv = *(const f4*)&ur[g * 4];
#pragma unroll
        for (int e = 0; e < 4; ++e) {
          int c = ch0 + g * 4 + e;
          float hv = uv[e] + Bs[w][c];
          hv = fmaxf(hv, 0.f) + a1 * fminf(hv, 0.f);
          h1[w][c * 32 + kslot] = hv;
        }
      }
    } else {
#pragma unroll
      for (int g = 0; g < 32; ++g) h1[w][(ch0 + g) * 32 + kslot] = 0.f;
    }
  }
  __syncthreads();

  // GEMM2: lane = kg*8+cg, tile 4nb x 8ch over padded 32 neighbors
  const int kg = l >> 3, cg = l & 7;
  const int k0 = kg * 4, c0 = cg * 8;
  float acc[4][8];
#pragma unroll
  for (int a = 0; a < 4; ++a)
#pragma unroll
    for (int b = 0; b < 8; ++b) acc[a][b] = 0.f;
#pragma unroll 4
  for (int c = 0; c < 64; ++c) {
    f4 hv = *(const f4*)&h1[w][c * 32 + k0];
    f4 w0 = *(const f4*)&W2s[c * 64 + c0];
    f4 w1 = *(const f4*)&W2s[c * 64 + c0 + 4];
    float wr[8] = {w0[0], w0[1], w0[2], w0[3], w1[0], w1[1], w1[2], w1[3]};
#pragma unroll
    for (int a = 0; a < 4; ++a)
#pragma unroll
      for (int b = 0; b < 8; ++b)
        acc[a][b] = fmaf(hv[a], wr[b], acc[a][b]);
  }

  // prelu + masked max (20 = 5 full groups of 4; kg>=5 are pad)
  float mx[8];
#pragma unroll
  for (int b = 0; b < 8; ++b) mx[b] = -FLT_MAX;
  if (kg < 5) {
#pragma unroll
    for (int a = 0; a < 4; ++a)
#pragma unroll
      for (int b = 0; b < 8; ++b) {
        float v = fmaxf(acc[a][b], 0.f) + a2 * fminf(acc[a][b], 0.f);
        mx[b] = fmaxf(mx[b], v);
      }
  }
#pragma unroll
  for (int b = 0; b < 8; ++b) {
    mx[b] = fmaxf(mx[b], __shfl_xor(mx[b], 8));
    mx[b] = fmaxf(mx[b], __shfl_xor(mx[b], 16));
    mx[b] = fmaxf(mx[b], __shfl_xor(mx[b], 32));
  }
  if (kg == 0) {
    f4 o0 = {mx[0], mx[1], mx[2], mx[3]}, o1 = {mx[4], mx[5], mx[6], mx[7]};
    float* yp = &Y[(size_t)i * ldy + c0];
    *(f4*)yp = o0;
    *(f4*)(yp + 4) = o1;
  }
}

// ---------------- edgeconv ONE-layer: out[i][c] = max_k prelu(U[nb][c]+B[i][c]) ----
__global__ __launch_bounds__(256, 4)
void edgeconv1_kernel(const float* __restrict__ UB, const int* __restrict__ ind,
                      const float* __restrict__ p1p, float* __restrict__ Y, int ldy) {
  __shared__ int nbs[4][KK];
  __shared__ float Bs[4][64];
  const int t = threadIdx.x;
  const int w = t >> 6, l = t & 63;
  const float a1 = *p1p;
  const int i = blockIdx.x * 4 + w;
  if (l < KK) nbs[w][l] = ind[i * KK + l];
  if (l < 16) *(f4*)&Bs[w][l * 4] = *(const f4*)&UB[(size_t)i * 128 + 64 + l * 4];
  __syncthreads();
  const float b = Bs[w][l];
  float mx = -FLT_MAX;
#pragma unroll 4
  for (int k = 0; k < KK; ++k) {
    float uv = UB[(size_t)nbs[w][k] * 128 + l];
    float hv = uv + b;
    hv = fmaxf(hv, 0.f) + a1 * fminf(hv, 0.f);
    mx = fmaxf(mx, hv);
  }
  Y[(size_t)i * ldy + l] = mx;
}

// ---------------- ordered-float encode for atomicMax ----------------
__device__ __forceinline__ unsigned fenc(float f) {
  unsigned u = __float_as_uint(f);
  return (u & 0x80000000u) ? ~u : (u | 0x80000000u);
}
__device__ __forceinline__ float fdec(unsigned u) {
  return (u & 0x80000000u) ? __uint_as_float(u & 0x7fffffffu) : __uint_as_float(~u);
}

__global__ void initg_kernel(unsigned* __restrict__ g) {
  g[blockIdx.x * 256 + threadIdx.x] = 0x007FFFFFu;  // fenc(-inf)
}

// ---------------- split fp32 -> (hi, lo) bf16, flat over n8 groups of 8 ----------
__global__ __launch_bounds__(256)
void splitA_kernel(const float* __restrict__ X, int n8,
                   short* __restrict__ hi, short* __restrict__ lo) {
  int idx = blockIdx.x * 256 + threadIdx.x;
  if (idx >= n8) return;
  f4 a = *(const f4*)&X[(size_t)idx * 8];
  f4 b = *(const f4*)&X[(size_t)idx * 8 + 4];
  bh8 h, w;
#pragma unroll
  for (int e = 0; e < 4; ++e) {
    float v0 = a[e], v1 = b[e];
    __hip_bfloat16 h0 = __float2bfloat16(v0);
    __hip_bfloat16 h1 = __float2bfloat16(v1);
    __hip_bfloat16 l0 = __float2bfloat16(v0 - __bfloat162float(h0));
    __hip_bfloat16 l1 = __float2bfloat16(v1 - __bfloat162float(h1));
    h[e] = *reinterpret_cast<short*>(&h0); h[4 + e] = *reinterpret_cast<short*>(&h1);
    w[e] = *reinterpret_cast<short*>(&l0); w[4 + e] = *reinterpret_cast<short*>(&l1);
  }
  *(bh8*)&hi[(size_t)idx * 8] = h;
  *(bh8*)&lo[(size_t)idx * 8] = w;
}

// ---------------- split + transpose W [K,ldw] -> Wt hi/lo [M][K] bf16 -------------
__global__ __launch_bounds__(256)
void splitWt_kernel(const float* __restrict__ W, int ldw, int M, int K,
                    short* __restrict__ hi, short* __restrict__ lo) {
  int idx = blockIdx.x * 256 + threadIdx.x;   // (c, kgroup8)
  int kg8 = K / 8;
  if (idx >= M * kg8) return;
  int c = idx / kg8, kg = idx - c * kg8;
  bh8 h, w;
#pragma unroll
  for (int e = 0; e < 8; ++e) {
    float v = W[(size_t)(kg * 8 + e) * ldw + c];
    __hip_bfloat16 hv = __float2bfloat16(v);
    __hip_bfloat16 lv = __float2bfloat16(v - __bfloat162float(hv));
    h[e] = *reinterpret_cast<short*>(&hv);
    w[e] = *reinterpret_cast<short*>(&lv);
  }
  *(bh8*)&hi[(size_t)c * K + kg * 8] = h;
  *(bh8*)&lo[(size_t)c * K + kg * 8] = w;
}

// ---------------- split-bf16 MFMA GEMM + prelu; MODE 1: colmax, MODE 2: bias+store -
template<int MODE, int K>
__global__ __launch_bounds__(256, 2)
void gemm_mfma_kernel(const short* __restrict__ Ahi, const short* __restrict__ Alo,
                      const short* __restrict__ Wthi, const short* __restrict__ Wtlo,
                      const float* __restrict__ bias, const float* __restrict__ pptr,
                      float* __restrict__ Cm, int ldc, unsigned* __restrict__ gmax) {
  __shared__ __align__(16) short Ah[128 * 32], Al[128 * 32];
  __shared__ __align__(16) short Bh[128 * 32], Bl[128 * 32];   // 32 KB total
  const int t = threadIdx.x;
  const int rb = blockIdx.x * 128, cb = blockIdx.y * 128;
  const float aa = *pptr;
  const int w = t >> 6, l = t & 63;
  const int rsub = (w >> 1) * 64, csub = (w & 1) * 64;
  const int lr = l & 15, lh = l >> 4;

  f32x4 acc[4][4];
#pragma unroll
  for (int i = 0; i < 4; ++i)
#pragma unroll
    for (int j = 0; j < 4; ++j) acc[i][j] = f32x4{0.f, 0.f, 0.f, 0.f};

  for (int ck = 0; ck < K; ck += 32) {
    __syncthreads();
#pragma unroll
    for (int u = 0; u < 2; ++u) {
      int idx = u * 256 + t;          // 0..511 = 128 rows x 4 slots
      int row = idx >> 2, s = idx & 3;
      int ssw = s ^ (row & 3);
      *(bh8*)&Ah[row * 32 + ssw * 8] = *(const bh8*)&Ahi[(size_t)(rb + row) * K + ck + s * 8];
      *(bh8*)&Al[row * 32 + ssw * 8] = *(const bh8*)&Alo[(size_t)(rb + row) * K + ck + s * 8];
      *(bh8*)&Bh[row * 32 + ssw * 8] = *(const bh8*)&Wthi[(size_t)(cb + row) * K + ck + s * 8];
      *(bh8*)&Bl[row * 32 + ssw * 8] = *(const bh8*)&Wtlo[(size_t)(cb + row) * K + ck + s * 8];
    }
    __syncthreads();
    bh8 ah[4], al[4], bh_[4], bl_[4];
#pragma unroll
    for (int i = 0; i < 4; ++i) {
      int r = rsub + i * 16 + lr;
      int ssw = lh ^ (r & 3);
      ah[i] = *(const bh8*)&Ah[r * 32 + ssw * 8];
      al[i] = *(const bh8*)&Al[r * 32 + ssw * 8];
      int c = csub + i * 16 + lr;
      int csw = lh ^ (c & 3);
      bh_[i] = *(const bh8*)&Bh[c * 32 + csw * 8];
      bl_[i] = *(const bh8*)&Bl[c * 32 + csw * 8];
    }
#pragma unroll
    for (int i = 0; i < 4; ++i)
#pragma unroll
      for (int j = 0; j < 4; ++j) {
        acc[i][j] = __builtin_amdgcn_mfma_f32_16x16x32_bf16(ah[i], bh_[j], acc[i][j], 0, 0, 0);
        acc[i][j] = __builtin_amdgcn_mfma_f32_16x16x32_bf16(ah[i], bl_[j], acc[i][j], 0, 0, 0);
        acc[i][j] = __builtin_amdgcn_mfma_f32_16x16x32_bf16(al[i], bh_[j], acc[i][j], 0, 0, 0);
      }
  }

  if (MODE == 1) {   // prelu + column max -> gmax (fenc atomic)
    float cmax[4];
#pragma unroll
    for (int j = 0; j < 4; ++j) cmax[j] = -FLT_MAX;
#pragma unroll
    for (int i = 0; i < 4; ++i)
#pragma unroll
      for (int r = 0; r < 4; ++r)
#pragma unroll
        for (int j = 0; j < 4; ++j) {
          float v = acc[i][j][r];
          v = fmaxf(v, 0.f) + aa * fminf(v, 0.f);
          cmax[j] = fmaxf(cmax[j], v);
        }
#pragma unroll
    for (int j = 0; j < 4; ++j) {
      cmax[j] = fmaxf(cmax[j], __shfl_xor(cmax[j], 16));
      cmax[j] = fmaxf(cmax[j], __shfl_xor(cmax[j], 32));
    }
    if (l < 16) {
#pragma unroll
      for (int j = 0; j < 4; ++j)
        atomicMax(&gmax[cb + csub + j * 16 + l], fenc(cmax[j]));
    }
  } else {           // bias + prelu + store
#pragma unroll
    for (int i = 0; i < 4; ++i)
#pragma unroll
      for (int r = 0; r < 4; ++r) {
        const int row = rsub + i * 16 + lh * 4 + r;
#pragma unroll
        for (int j = 0; j < 4; ++j) {
          const int col = csub + j * 16 + lr;
          float v = acc[i][j][r] + bias[cb + col];
          v = fmaxf(v, 0.f) + aa * fminf(v, 0.f);
          Cm[(size_t)(rb + row) * ldc + cb + col] = v;
        }
      }
  }
}

// ---------------- generic fp32 GEMM + prelu; MODE: 0 store, 1 colmax, 2 bias+store ----
template<int MODE>
__global__ __launch_bounds__(256, 2)
void gemm_kernel(const float* __restrict__ A, int lda,
                 const float* __restrict__ W, int ldw,
                 const float* __restrict__ bias,
                 const float* __restrict__ pptr,
                 float* __restrict__ Cm, int ldc, int Ktot,
                 unsigned* __restrict__ gmax) {
  __shared__ __align__(16) float At[16 * 132];
  __shared__ __align__(16) float Ws[16 * 128];
  const int t = threadIdx.x;
  const int rb = blockIdx.x * 128, cbb = blockIdx.y * 128;
  const int r0 = (t & 15) * 8, c0 = (t >> 4) * 8;
  const float aa = *pptr;

  float acc[8][8];
#pragma unroll
  for (int i = 0; i < 8; ++i)
#pragma unroll
    for (int j = 0; j < 8; ++j) acc[i][j] = 0.f;

  const int sr = t >> 1, skh = (t & 1) * 8;
  const int wk = t >> 4, wc = (t & 15) * 8;

  for (int k0 = 0; k0 < Ktot; k0 += 16) {
    __syncthreads();
    {
      const float* ap = &A[(size_t)(rb + sr) * lda + k0 + skh];
      f4 v0 = *(const f4*)ap;
      f4 v1 = *(const f4*)(ap + 4);
#pragma unroll
      for (int e = 0; e < 4; ++e) {
        At[(skh + e) * 132 + sr] = v0[e];
        At[(skh + 4 + e) * 132 + sr] = v1[e];
      }
      const float* wp = &W[(size_t)(k0 + wk) * ldw + cbb + wc];
      *(f4*)&Ws[wk * 128 + wc] = *(const f4*)wp;
      *(f4*)&Ws[wk * 128 + wc + 4] = *(const f4*)(wp + 4);
    }
    __syncthreads();
#pragma unroll 4
    for (int d = 0; d < 16; ++d) {
      f4 qa = *(const f4*)&At[d * 132 + r0];
      f4 qb = *(const f4*)&At[d * 132 + r0 + 4];
      f4 wa = *(const f4*)&Ws[d * 128 + c0];
      f4 wb = *(const f4*)&Ws[d * 128 + c0 + 4];
      float qr[8] = {qa[0], qa[1], qa[2], qa[3], qb[0], qb[1], qb[2], qb[3]};
      float wr[8] = {wa[0], wa[1], wa[2], wa[3], wb[0], wb[1], wb[2], wb[3]};
#pragma unroll
      for (int i = 0; i < 8; ++i)
#pragma unroll
        for (int j = 0; j < 8; ++j)
          acc[i][j] = fmaf(qr[i], wr[j], acc[i][j]);
    }
  }

  float bv[8];
#pragma unroll
  for (int j = 0; j < 8; ++j) bv[j] = (MODE == 2) ? bias[cbb + c0 + j] : 0.f;
#pragma unroll
  for (int i = 0; i < 8; ++i)
#pragma unroll
    for (int j = 0; j < 8; ++j) {
      float v = acc[i][j] + bv[j];
      acc[i][j] = fmaxf(v, 0.f) + aa * fminf(v, 0.f);
    }

  if (MODE == 1) {
    float cmax[8];
#pragma unroll
    for (int j = 0; j < 8; ++j) {
      cmax[j] = acc[0][j];
#pragma unroll
      for (int i = 1; i < 8; ++i) cmax[j] = fmaxf(cmax[j], acc[i][j]);
    }
    __syncthreads();
#pragma unroll
    for (int j = 0; j < 8; ++j) At[(t & 15) * 132 + c0 + j] = cmax[j];
    __syncthreads();
    if (t < 128) {
      float m = At[t];
      for (int rr = 1; rr < 16; ++rr) m = fmaxf(m, At[rr * 132 + t]);
      atomicMax(&gmax[cbb + t], fenc(m));
    }
  } else {
#pragma unroll
    for (int i = 0; i < 8; ++i) {
      f4 s0 = {acc[i][0], acc[i][1], acc[i][2], acc[i][3]};
      f4 s1 = {acc[i][4], acc[i][5], acc[i][6], acc[i][7]};
      float* cp = &Cm[(size_t)(rb + r0 + i) * ldc + cbb + c0];
      *(f4*)cp = s0;
      *(f4*)(cp + 4) = s1;
    }
  }
}

// ---------------- bias5[c] = sum_j g[j] * W5[192+j][c] ----------------
__global__ void bias5_kernel(const unsigned* __restrict__ gmax, const float* __restrict__ W5,
                             float* __restrict__ bias5) {
  __shared__ float gs[1024];
  __shared__ float pm[4 * 256];
  int t = threadIdx.x;  // 1024 threads
  gs[t] = fdec(gmax[t]);
  __syncthreads();
  int c = t & 255, p = t >> 8;
  float acc = 0.f;
  for (int j = p * 256; j < p * 256 + 256; ++j)
    acc = fmaf(gs[j], W5[(size_t)(192 + j) * 256 + c], acc);
  pm[p * 256 + c] = acc;
  __syncthreads();
  if (t < 256) bias5[t] = pm[t] + pm[256 + t] + pm[512 + t] + pm[768 + t];
}

// ---------------- final [N,128]@[128,3] + prelu + hidden passthrough ----------------
__global__ __launch_bounds__(256, 2)
void w8_kernel(const float* __restrict__ A, const float* __restrict__ W8,
               const float* __restrict__ pptr, const float* __restrict__ hidden,
               float* __restrict__ out) {
  __shared__ __align__(16) float As[64 * 132];
  __shared__ float W8s[128 * COUT];
  int t = threadIdx.x;
  int rb = blockIdx.x * 64;
  for (int idx = t; idx < 128 * COUT; idx += 256) W8s[idx] = W8[idx];
  for (int idx = t; idx < 64 * 32; idx += 256) {
    int r = idx >> 5, c4 = idx & 31;
    *(f4*)&As[r * 132 + c4 * 4] = *(const f4*)&A[(size_t)(rb + r) * 128 + c4 * 4];
  }
  const float a = *pptr;
  __syncthreads();
  int r = t >> 2, c = t & 3;
  if (c < COUT) {
    float acc = 0.f;
#pragma unroll 8
    for (int j = 0; j < 128; ++j)
      acc = fmaf(As[r * 132 + j], W8s[j * COUT + c], acc);
    float v = fmaxf(acc, 0.f) + a * fminf(acc, 0.f);
    out[(size_t)(rb + r) * COUT + c] = v;
  }
  if (blockIdx.x == 0 && t == 0) out[(size_t)NPTS * COUT] = hidden[0];
}

// ---------------- host launch ----------------
extern "C" void kernel_launch(void* const* d_in, const int* in_sizes, int n_in,
                              void* d_out, int out_size, void* d_ws, size_t ws_size,
                              hipStream_t stream) {
  (void)in_sizes; (void)n_in; (void)out_size; (void)ws_size;
  const float* x      = (const float*)d_in[0];
  const float* hidden = (const float*)d_in[1];
  const float* W1a = (const float*)d_in[2];
  const float* p1a = (const float*)d_in[3];
  const float* W1b = (const float*)d_in[4];
  const float* p1b = (const float*)d_in[5];
  const float* W2a = (const float*)d_in[6];
  const float* p2a = (const float*)d_in[7];
  const float* W2b = (const float*)d_in[8];
  const float* p2b = (const float*)d_in[9];
  const float* W3  = (const float*)d_in[10];
  const float* p3  = (const float*)d_in[11];
  const float* W4  = (const float*)d_in[12];
  const float* p4  = (const float*)d_in[13];
  const float* W5  = (const float*)d_in[14];
  const float* p5  = (const float*)d_in[15];
  const float* W6  = (const float*)d_in[16];
  const float* p6  = (const float*)d_in[17];
  const float* W7  = (const float*)d_in[18];
  const float* p7  = (const float*)d_in[19];
  const float* W8  = (const float*)d_in[20];
  const float* p8  = (const float*)d_in[21];
  float* out = (float*)d_out;

  char* ws = (char*)d_ws;
  size_t off = 0;
  auto carve = [&](size_t bytes) -> void* {
    void* p = ws + off;
    off = (off + bytes + 255) & ~(size_t)255;
    return p;
  };
  float*    x4    = (float*)   carve((size_t)NPTS * 192 * 4);  // [x1|x2|x3], ld=192 (reused as h7)
  float*    vn    = (float*)   carve((size_t)NPTS * 4);
  float*    sn    = (float*)   carve((size_t)NPTS * 4);
  int*      ind   = (int*)     carve((size_t)NPTS * KK * 4);
  float*    T     = (float*)   carve((size_t)NPTS * 4);
  unsigned* cnt   = (unsigned*)carve((size_t)NPTS * 4);
  unsigned* redoCnt = (unsigned*)carve(256);
  int*      redoList = (int*)  carve((size_t)NPTS * 4);
  float*    rpd   = (float*)   carve((size_t)RQSLOTS * 32 * KK * 4);  // redo pass1 lists
  int*      rpi   = (int*)     carve((size_t)RQSLOTS * 32 * KK * 4);
  float*    meanb = (float*)   carve(64 * 4);
  float*    Xc    = (float*)   carve((size_t)NPTS * 64 * 4);   // centered fp32 slice
  short*    Xbf   = (short*)   carve((size_t)NPTS * 64 * 2);   // centered bf16 slice
  float*    plist = (float*)   carve((size_t)2 * NPTS * 64 * 4); // sampler lists; reused as UB
  short*    Ahi   = (short*)   carve((size_t)NPTS * 192 * 2);  // x4 split hi
  short*    Alo   = (short*)   carve((size_t)NPTS * 192 * 2);  // x4 split lo
  short*    Wt4h  = (short*)   carve((size_t)1024 * 192 * 2);
  short*    Wt4l  = (short*)   carve((size_t)1024 * 192 * 2);
  short*    Wt5h  = (short*)   carve((size_t)256 * 192 * 2);
  short*    Wt5l  = (short*)   carve((size_t)256 * 192 * 2);
  unsigned* gmax  = (unsigned*)carve(1024 * 4);
  float*    bias5 = (float*)   carve(256 * 4);
  float*    h5    = (float*)   carve((size_t)NPTS * 256 * 4);  // aliased: survd (knn phase)
  float*    h6    = (float*)   carve((size_t)NPTS * 256 * 4);  // aliased: survi (knn phase)
  float* survd = h5;
  int*   survi = (int*)h6;
  float* h7 = x4;   // x4 dead after W5 GEMM
  float* UB = plist; // plist dead after mergeT; UB = [N][128] (U|B), same size

  // ---- stage 1: knn(x, C=3, reg-query filter) + edgeconv1 -> x4[:, 0:64] ----
  norms_kernel<3><<<64, 256, 0, stream>>>(x, 3, vn);
  sampleTv4_kernel<3><<<dim3(256, 2), 256, 0, stream>>>(x, vn, plist);
  mergeT_kernel<<<64, 256, 0, stream>>>(plist, T, cnt, redoCnt);
  knn_filter3_kernel<<<dim3(128, 8), 256, 0, stream>>>(x, vn, T, survd, survi, cnt);
  select_kernel<<<64, 256, 0, stream>>>(survd, survi, cnt, ind, redoCnt, redoList);
  knn_redo_p1<3><<<RQSLOTS * 32, 256, 0, stream>>>(x, 3, vn, redoList, redoCnt, rpd, rpi);
  knn_redo_p2<<<1, 256, 0, stream>>>(redoList, redoCnt, rpd, rpi, ind);
  knn_redo_kernel<3><<<256, 256, 0, stream>>>(x, 3, vn, redoList, redoCnt, ind, RQSLOTS);
  ub_kernel<3><<<512, 256, 0, stream>>>(x, 3, W1a, UB);
  edgeconv2_kernel<<<4096, 256, 0, stream>>>(UB, ind, W1b, p1a, p1b, x4 + 0, 192);

  // ---- stage 2: knn(x1 centered, MFMA filter) + edgeconv2 -> x4[:, 64:128] ----
  mean64_kernel<<<64, 256, 0, stream>>>(x4 + 0, 192, meanb);
  xc_kernel<<<512, 256, 0, stream>>>(x4 + 0, 192, meanb, Xc, Xbf, vn, sn);
  sampleTv4_kernel<64><<<dim3(256, 2), 256, 0, stream>>>(Xc, vn, plist);
  mergeT_kernel<<<64, 256, 0, stream>>>(plist, T, cnt, redoCnt);
  knn_filter64_mfma<<<dim3(128, 64), 256, 0, stream>>>(Xbf, vn, sn, T, survi, cnt);
  exact_kernel<64><<<NPTS, 256, 0, stream>>>(Xc, 64, vn, cnt, survi, survd);
  select_kernel<<<64, 256, 0, stream>>>(survd, survi, cnt, ind, redoCnt, redoList);
  knn_redo_p1<64><<<RQSLOTS * 32, 256, 0, stream>>>(Xc, 64, vn, redoList, redoCnt, rpd, rpi);
  knn_redo_p2<<<1, 256, 0, stream>>>(redoList, redoCnt, rpd, rpi, ind);
  knn_redo_kernel<64><<<256, 256, 0, stream>>>(Xc, 64, vn, redoList, redoCnt, ind, RQSLOTS);
  ub_kernel<64><<<512, 256, 0, stream>>>(x4 + 0, 192, W2a, UB);
  edgeconv2_kernel<<<4096, 256, 0, stream>>>(UB, ind, W2b, p2a, p2b, x4 + 64, 192);

  // ---- stage 3: knn(x2 centered, MFMA filter) + edgeconv3 -> x4[:, 128:192] ----
  mean64_kernel<<<64, 256, 0, stream>>>(x4 + 64, 192, meanb);
  xc_kernel<<<512, 256, 0, stream>>>(x4 + 64, 192, meanb, Xc, Xbf, vn, sn);
  sampleTv4_kernel<64><<<dim3(256, 2), 256, 0, stream>>>(Xc, vn, plist);
  mergeT_kernel<<<64, 256, 0, stream>>>(plist, T, cnt, redoCnt);
  knn_filter64_mfma<<<dim3(128, 64), 256, 0, stream>>>(Xbf, vn, sn, T, survi, cnt);
  exact_kernel<64><<<NPTS, 256, 0, stream>>>(Xc, 64, vn, cnt, survi, survd);
  select_kernel<<<64, 256, 0, stream>>>(survd, survi, cnt, ind, redoCnt, redoList);
  knn_redo_p1<64><<<RQSLOTS * 32, 256, 0, stream>>>(Xc, 64, vn, redoList, redoCnt, rpd, rpi);
  knn_redo_p2<<<1, 256, 0, stream>>>(redoList, redoCnt, rpd, rpi, ind);
  knn_redo_kernel<64><<<256, 256, 0, stream>>>(Xc, 64, vn, redoList, redoCnt, ind, RQSLOTS);
  ub_kernel<64><<<512, 256, 0, stream>>>(x4 + 64, 192, W3, UB);
  edgeconv1_kernel<<<4096, 256, 0, stream>>>(UB, ind, p3, x4 + 128, 192);

  // ---- split x4 / W4 / W5 into bf16 hi+lo for MFMA tail ----
  splitA_kernel<<<(NPTS * 192 / 8 + 255) / 256, 256, 0, stream>>>(x4, NPTS * 192 / 8, Ahi, Alo);
  splitWt_kernel<<<(1024 * 24 + 255) / 256, 256, 0, stream>>>(W4, 1024, 1024, 192, Wt4h, Wt4l);
  splitWt_kernel<<<(256 * 24 + 255) / 256, 256, 0, stream>>>(W5, 256, 256, 192, Wt5h, Wt5l);

  // ---- x5 = prelu(x4@W4); g = colmax(x5)  [split-bf16 MFMA] ----
  initg_kernel<<<4, 256, 0, stream>>>(gmax);
  gemm_mfma_kernel<1, 192><<<dim3(128, 8), 256, 0, stream>>>(Ahi, Alo, Wt4h, Wt4l, nullptr, p4, nullptr, 0, gmax);

  // ---- bias5 = g @ W5[192:1216] ----
  bias5_kernel<<<1, 1024, 0, stream>>>(gmax, W5, bias5);

  // ---- h5 = prelu(x4@W5[0:192] + bias5)  [split-bf16 MFMA] ----
  gemm_mfma_kernel<2, 192><<<dim3(128, 2), 256, 0, stream>>>(Ahi, Alo, Wt5h, Wt5l, bias5, p5, h5, 256, nullptr);
  // ---- h6 = prelu(h5@W6) ----
  gemm_kernel<0><<<dim3(128, 2), 256, 0, stream>>>(h5, 256, W6, 256, nullptr, p6, h6, 256, 256, nullptr);
  // ---- h7 = prelu(h6@W7) ----
  gemm_kernel<0><<<dim3(128, 1), 256, 0, stream>>>(h6, 256, W7, 128, nullptr, p7, h7, 128, 256, nullptr);
  // ---- out = prelu(h7@W8); out[N*3] = hidden ----
  w8_kernel<<<256, 256, 0, stream>>>(h7, W8, p8, hidden, out);
}

// Round 19
// 1822.957 us; speedup vs baseline: 1.0869x; 1.0869x over previous
//
#include <hip/hip_runtime.h>
#include <hip/hip_bf16.h>
#include <float.h>

#define NPTS 16384
#define KK 20
#define COUT 3
#define SURV_CAP 256
#define RQSLOTS 256

typedef float f4 __attribute__((ext_vector_type(4)));
typedef float f32x4 __attribute__((ext_vector_type(4)));
typedef short bh8 __attribute__((ext_vector_type(8)));   // 8 bf16 in 4 VGPRs

// ---------------- sorted top-20 insert, values only ----------------
__device__ __forceinline__ void ins20(float (&td)[KK], float &kmax, float nd) {
  float cd = nd;
#pragma unroll
  for (int j = 0; j < KK; ++j) {
    float t0 = td[j];
    bool lt = cd < t0;
    td[j] = lt ? cd : t0;
    cd = lt ? t0 : cd;
  }
  kmax = td[KK - 1];
}

// ---------------- sorted top-4 insert, values only ----------------
__device__ __forceinline__ void ins4(float (&td)[4], float &kmax, float nd) {
  float cd = nd;
#pragma unroll
  for (int j = 0; j < 4; ++j) {
    float t0 = td[j];
    bool lt = cd < t0;
    td[j] = lt ? cd : t0;
    cd = lt ? t0 : cd;
  }
  kmax = td[3];
}

// ---------------- sorted top-20 insert, (value, index) ----------------
__device__ __forceinline__ void ins20p(float (&td)[KK], int (&ti)[KK],
                                       float &kmax, float nd, int ni) {
  float cd = nd; int ci = ni;
#pragma unroll
  for (int j = 0; j < KK; ++j) {
    float t0 = td[j]; int t1 = ti[j];
    bool lt = cd < t0;
    td[j] = lt ? cd : t0;  ti[j] = lt ? ci : t1;
    cd = lt ? t0 : cd;     ci = lt ? t1 : ci;
  }
  kmax = td[KK - 1];
}

// ---------------- row squared norms (stage-1 / C=3 path) ----------------
template<int C>
__global__ void norms_kernel(const float* __restrict__ X, int ldx, float* __restrict__ vn) {
  int i = blockIdx.x * 256 + threadIdx.x;
  if (i >= NPTS) return;
  const float* row = X + (size_t)i * ldx;
  float s = 0.f;
#pragma unroll
  for (int c = 0; c < C; ++c) s = fmaf(row[c], row[c], s);
  vn[i] = s;
}

// ---------------- deterministic column mean over 64 dims ----------------
__global__ __launch_bounds__(256)
void mean64_kernel(const float* __restrict__ X, int ldx, float* __restrict__ mean) {
  __shared__ float p[256];
  const int d = blockIdx.x, t = threadIdx.x;
  float s = 0.f;
  for (int r = t; r < NPTS; r += 256) s += X[(size_t)r * ldx + d];
  p[t] = s;
  __syncthreads();
  for (int o = 128; o > 0; o >>= 1) { if (t < o) p[t] += p[t + o]; __syncthreads(); }
  if (t == 0) mean[d] = p[0] * (1.0f / NPTS);
}

// ---------------- center + fp32 copy + bf16 copy + vn + sn  (64-dim slice) --------
__global__ __launch_bounds__(256)
void xc_kernel(const float* __restrict__ X, int ldx, const float* __restrict__ mean,
               float* __restrict__ Xc, short* __restrict__ Xbf,
               float* __restrict__ vn, float* __restrict__ sn) {
  __shared__ float msh[64];
  const int t = threadIdx.x;
  if (t < 64) msh[t] = mean[t];
  __syncthreads();
  const int row = blockIdx.x * 32 + (t >> 3), sub = t & 7;
  f4 a = *(const f4*)&X[(size_t)row * ldx + sub * 8];
  f4 b = *(const f4*)&X[(size_t)row * ldx + sub * 8 + 4];
#pragma unroll
  for (int e = 0; e < 4; ++e) { a[e] -= msh[sub * 8 + e]; b[e] -= msh[sub * 8 + 4 + e]; }
  *(f4*)&Xc[(size_t)row * 64 + sub * 8] = a;
  *(f4*)&Xc[(size_t)row * 64 + sub * 8 + 4] = b;
  bh8 o;
#pragma unroll
  for (int e = 0; e < 4; ++e) {
    __hip_bfloat16 ha = __float2bfloat16(a[e]);
    __hip_bfloat16 hb = __float2bfloat16(b[e]);
    o[e] = *reinterpret_cast<short*>(&ha);
    o[4 + e] = *reinterpret_cast<short*>(&hb);
  }
  *(bh8*)&Xbf[(size_t)row * 64 + sub * 8] = o;
  float s = a[0]*a[0] + a[1]*a[1] + a[2]*a[2] + a[3]*a[3]
          + b[0]*b[0] + b[1]*b[1] + b[2]*b[2] + b[3]*b[3];
  s += __shfl_xor(s, 1);
  s += __shfl_xor(s, 2);
  s += __shfl_xor(s, 4);
  if (sub == 0) { vn[row] = s; sn[row] = sqrtf(s); }
}

// ---------------- phase S v4: tiled sampler -> per-thread top-4 lists -------------
template<int C>
__global__ __launch_bounds__(256, 2)
void sampleTv4_kernel(const float* __restrict__ X, const float* __restrict__ vn,
                      float* __restrict__ plist) {
  __shared__ __align__(16) float Qs[C * 64];     // dim-major [d][q]
  __shared__ __align__(16) float Cs[C * 132];    // dim-major [d][r], pad->132
  __shared__ float cn[128];
  const int t = threadIdx.x;
  const int qb = blockIdx.x * 64;
  const int tb = blockIdx.y ? 11 : 0;
  const int nt = blockIdx.y ? 10 : 11;           // 21 tiles total

  if constexpr (C == 64) {
#pragma unroll
    for (int u = 0; u < 4; ++u) {
      int idx = u * 256 + t;
      int q = idx & 63, dg = idx >> 6;
      f4 v = *(const f4*)&X[(size_t)(qb + q) * C + dg * 4];
#pragma unroll
      for (int e = 0; e < 4; ++e) Qs[(dg * 4 + e) * 64 + q] = v[e];
    }
  } else {
    for (int idx = t; idx < C * 64; idx += 256) {
      int q = idx & 63, d = idx >> 6;
      Qs[d * 64 + q] = X[(size_t)(qb + q) * C + d];
    }
  }

  const int tq = t & 15, tc = t >> 4;
  const int q0 = tq * 4, c0 = tc * 8;

  float l4[4][4]; float km[4];
#pragma unroll
  for (int i = 0; i < 4; ++i) {
    km[i] = FLT_MAX;
#pragma unroll
    for (int k = 0; k < 4; ++k) l4[i][k] = FLT_MAX;
  }

  for (int tt = 0; tt < nt; ++tt) {
    const int base = (tb + tt) * 128;
    __syncthreads();
    if constexpr (C == 64) {
#pragma unroll
      for (int u = 0; u < 8; ++u) {
        int idx = u * 256 + t;
        int r = idx & 127, dg = idx >> 7;
        f4 v = *(const f4*)&X[(size_t)((base + r) * 6) * C + dg * 4];
#pragma unroll
        for (int e = 0; e < 4; ++e) Cs[(dg * 4 + e) * 132 + r] = v[e];
      }
    } else {
      for (int idx = t; idx < C * 128; idx += 256) {
        int r = idx & 127, d = idx >> 7;
        Cs[d * 132 + r] = X[(size_t)((base + r) * 6) * C + d];
      }
    }
    if (t < 128) cn[t] = vn[(base + t) * 6];
    __syncthreads();

    float acc[4][8];
#pragma unroll
    for (int i = 0; i < 4; ++i)
#pragma unroll
      for (int j = 0; j < 8; ++j) acc[i][j] = 0.f;

#pragma unroll 4
    for (int d = 0; d < C; ++d) {
      f4 qa = *(const f4*)&Qs[d * 64 + q0];
      f4 ca = *(const f4*)&Cs[d * 132 + c0];
      f4 cb = *(const f4*)&Cs[d * 132 + c0 + 4];
      float cr[8] = {ca[0], ca[1], ca[2], ca[3], cb[0], cb[1], cb[2], cb[3]};
#pragma unroll
      for (int i = 0; i < 4; ++i)
#pragma unroll
        for (int j = 0; j < 8; ++j)
          acc[i][j] = fmaf(qa[i], cr[j], acc[i][j]);
    }

#pragma unroll
    for (int j = 0; j < 8; ++j) {
      float cv = cn[c0 + j];
#pragma unroll
      for (int i = 0; i < 4; ++i) {
        float sv = fmaf(-2.f, acc[i][j], cv);
        if (sv < km[i]) ins4(l4[i], km[i], sv);
      }
    }
  }

#pragma unroll
  for (int i = 0; i < 4; ++i) {
    size_t off = (((size_t)blockIdx.y * NPTS + (qb + q0 + i)) * 16 + tc) * 4;
    f4 v = {l4[i][0], l4[i][1], l4[i][2], l4[i][3]};
    *(f4*)&plist[off] = v;
  }
}

// ---------------- merge plist -> T; zero cnt/redoCnt ----------------
__global__ __launch_bounds__(256)
void mergeT_kernel(const float* __restrict__ plist, float* __restrict__ T,
                   unsigned* __restrict__ cnt, unsigned* __restrict__ redoCnt) {
  const int q = blockIdx.x * 256 + threadIdx.x;
  float td[KK];
#pragma unroll
  for (int j = 0; j < KK; ++j) td[j] = FLT_MAX;
  float km = FLT_MAX;
  for (int s = 0; s < 2; ++s) {
    const float* p = &plist[((size_t)s * NPTS + q) * 64];
    for (int z = 0; z < 64; ++z) {
      float v = p[z];
      if (v < km) ins20(td, km, v);
    }
  }
  T[q] = td[KK - 1] + 1e-4f * (fabsf(td[KK - 1]) + 1.0f);
  cnt[q] = 0u;
  if (q == 0) *redoCnt = 0u;
}

// ---------------- phase F (C=3): register-query filter + LDS survivor aggregation --
// CAPB=28 keeps LDS ~37 KB -> 4 blocks/CU. Overflow falls back to global append.
__global__ __launch_bounds__(256, 4)
void knn_filter3_kernel(const float* __restrict__ X, const float* __restrict__ vn,
                        const float* __restrict__ T,
                        float* __restrict__ survd, int* __restrict__ survi,
                        unsigned* __restrict__ cnt) {
  constexpr int CAPB = 28;
  __shared__ __align__(16) f4 CsV[512];            // (x,y,z,vn) packed, 8 KB
  __shared__ float Tsl[128];
  __shared__ unsigned scnt[128];
  __shared__ float sbD[128 * CAPB];
  __shared__ int   sbI[128 * CAPB];

  const int t = threadIdx.x;
  const int qb = blockIdx.x * 128;
  const int cbase = blockIdx.y * 2048;
  if (t < 128) { Tsl[t] = T[qb + t]; scnt[t] = 0u; }
  __syncthreads();

  const int tq = t & 15, tc = t >> 4;
  const int q0 = tq * 8, c0loc = tc * 8;

  float qx[8], qy[8], qz[8], tr[8];
#pragma unroll
  for (int i = 0; i < 8; ++i) {
    const float* qr = &X[(size_t)(qb + q0 + i) * 3];
    qx[i] = qr[0]; qy[i] = qr[1]; qz[i] = qr[2];
    tr[i] = Tsl[q0 + i];
  }

  for (int rd = 0; rd < 4; ++rd) {
    const int cb = cbase + rd * 512;
    __syncthreads();   // prior round's CsV reads done
#pragma unroll
    for (int u = 0; u < 2; ++u) {
      int idx = u * 256 + t;
      int c = cb + idx;
      const float* cr = &X[(size_t)c * 3];
      f4 v = {cr[0], cr[1], cr[2], vn[c]};
      CsV[idx] = v;
    }
    __syncthreads();

#pragma unroll
    for (int sub = 0; sub < 4; ++sub) {
      const int cl0 = sub * 128 + c0loc;
#pragma unroll
      for (int j = 0; j < 8; ++j) {
        f4 cv = CsV[cl0 + j];
        const int cglob = cb + cl0 + j;
#pragma unroll
        for (int i = 0; i < 8; ++i) {
          float d0 = fmaf(qx[i], cv[0], fmaf(qy[i], cv[1], qz[i] * cv[2]));
          float sv = fmaf(-2.f, d0, cv[3]);
          if (sv <= tr[i]) {
            unsigned p = atomicAdd(&scnt[q0 + i], 1u);
            if (p < CAPB) {
              sbD[(q0 + i) * CAPB + p] = sv;
              sbI[(q0 + i) * CAPB + p] = cglob;
            } else {  // rare fallback: direct global append
              unsigned gp = atomicAdd(&cnt[qb + q0 + i], 1u);
              if (gp < SURV_CAP) {
                survd[(size_t)(qb + q0 + i) * SURV_CAP + gp] = sv;
                survi[(size_t)(qb + q0 + i) * SURV_CAP + gp] = cglob;
              }
            }
          }
        }
      }
    }
  }

  __syncthreads();
  if (t < 128) {
    unsigned n = scnt[t]; if (n > CAPB) n = CAPB;
    if (n) {
      unsigned base = atomicAdd(&cnt[qb + t], n);
      for (unsigned i = 0; i < n; ++i) {
        unsigned p = base + i;
        if (p < SURV_CAP) {
          survd[(size_t)(qb + t) * SURV_CAP + p] = sbD[t * CAPB + i];
          survi[(size_t)(qb + t) * SURV_CAP + p] = sbI[t * CAPB + i];
        }
      }
    }
  }
}

// ---------------- phase F (C=64): MFMA bf16 filter + LDS survivor aggregation ------
__global__ __launch_bounds__(256, 2)
void knn_filter64_mfma(const short* __restrict__ Xbf, const float* __restrict__ vn,
                       const float* __restrict__ sn, const float* __restrict__ T,
                       int* __restrict__ survi, unsigned* __restrict__ cnt) {
  __shared__ __align__(16) short Qs[128 * 64];
  __shared__ __align__(16) short Cs[128 * 64];
  __shared__ float vnc[128], snq[128], snc[128], Tq[128];
  __shared__ unsigned scnt[128];
  __shared__ int sbI[128 * 8];

  const int t = threadIdx.x;
  const int qb = blockIdx.x * 128, cb = blockIdx.y * 128;

#pragma unroll
  for (int p = 0; p < 4; ++p) {
    int idx = p * 256 + t;
    int row = idx >> 3, sl = idx & 7;
    int slq = sl ^ (row & 7);
    *(bh8*)&Qs[row * 64 + slq * 8] = *(const bh8*)&Xbf[(size_t)(qb + row) * 64 + sl * 8];
    *(bh8*)&Cs[row * 64 + slq * 8] = *(const bh8*)&Xbf[(size_t)(cb + row) * 64 + sl * 8];
  }
  if (t < 128) { Tq[t] = T[qb + t]; snq[t] = sn[qb + t]; scnt[t] = 0u; }
  else { vnc[t - 128] = vn[cb + t - 128]; snc[t - 128] = sn[cb + t - 128]; }
  __syncthreads();

  const int w = t >> 6, l = t & 63;
  const int qsub = (w >> 1) * 64, csub = (w & 1) * 64;
  const int lr = l & 15, lh = l >> 4;

  f32x4 acc[4][4];
#pragma unroll
  for (int i = 0; i < 4; ++i)
#pragma unroll
    for (int j = 0; j < 4; ++j) acc[i][j] = f32x4{0.f, 0.f, 0.f, 0.f};

#pragma unroll
  for (int kk = 0; kk < 2; ++kk) {
    const int sl = kk * 4 + lh;
    bh8 af[4], bf[4];
#pragma unroll
    for (int i = 0; i < 4; ++i) {
      int qr = qsub + i * 16 + lr;
      af[i] = *(const bh8*)&Qs[qr * 64 + (sl ^ (qr & 7)) * 8];
      int cr = csub + i * 16 + lr;
      bf[i] = *(const bh8*)&Cs[cr * 64 + (sl ^ (cr & 7)) * 8];
    }
#pragma unroll
    for (int i = 0; i < 4; ++i)
#pragma unroll
      for (int j = 0; j < 4; ++j)
        acc[i][j] = __builtin_amdgcn_mfma_f32_16x16x32_bf16(af[i], bf[j], acc[i][j], 0, 0, 0);
  }

#pragma unroll
  for (int i = 0; i < 4; ++i) {
#pragma unroll
    for (int r = 0; r < 4; ++r) {
      const int ql = qsub + i * 16 + lh * 4 + r;
      const float tcut = Tq[ql];
      const float sq = snq[ql];
      const int q = qb + ql;
#pragma unroll
      for (int j = 0; j < 4; ++j) {
        const int cl = csub + j * 16 + lr;
        float s = fmaf(-2.f, acc[i][j][r], vnc[cl]);
        float margin = 0.0082f * sq * snc[cl] + 1e-6f;
        if (s <= tcut + margin) {
          unsigned p = atomicAdd(&scnt[ql], 1u);
          if (p < 8u) sbI[ql * 8 + p] = cb + cl;
          else {  // rare fallback
            unsigned gp = atomicAdd(&cnt[q], 1u);
            if (gp < SURV_CAP) survi[(size_t)q * SURV_CAP + gp] = cb + cl;
          }
        }
      }
    }
  }

  __syncthreads();
  if (t < 128) {
    unsigned n = scnt[t]; if (n > 8u) n = 8u;
    if (n) {
      unsigned base = atomicAdd(&cnt[qb + t], n);
      for (unsigned i = 0; i < n; ++i) {
        unsigned p = base + i;
        if (p < SURV_CAP) survi[(size_t)(qb + t) * SURV_CAP + p] = sbI[t * 8 + i];
      }
    }
  }
}

// ---------------- exact fp32 recompute of survivor distances (C=64 path) ----------
template<int C>
__global__ __launch_bounds__(256, 2)
void exact_kernel(const float* __restrict__ X, int ldx, const float* __restrict__ vn,
                  const unsigned* __restrict__ cnt, const int* __restrict__ survi,
                  float* __restrict__ survd) {
  __shared__ float qsh[C];
  const int q = blockIdx.x;
  const int t = threadIdx.x;
  if (t < C) qsh[t] = X[(size_t)q * ldx + t];
  __syncthreads();
  unsigned n = cnt[q];
  if (n > SURV_CAP) n = SURV_CAP;
  if (t < n) {
    const int c = survi[(size_t)q * SURV_CAP + t];
    const float* crow = X + (size_t)c * ldx;
    float d0 = 0.f, d1 = 0.f, d2 = 0.f, d3 = 0.f;
#pragma unroll
    for (int s = 0; s < C / 4; ++s) {
      f4 cv = *(const f4*)&crow[s * 4];
      d0 = fmaf(cv[0], qsh[s * 4 + 0], d0);
      d1 = fmaf(cv[1], qsh[s * 4 + 1], d1);
      d2 = fmaf(cv[2], qsh[s * 4 + 2], d2);
      d3 = fmaf(cv[3], qsh[s * 4 + 3], d3);
    }
    survd[(size_t)q * SURV_CAP + t] = fmaf(-2.f, (d0 + d1) + (d2 + d3), vn[c]);
  }
}

// ---------------- phase Sel: exact top-20 among survivors (overflow -> redo list) --
__global__ __launch_bounds__(256, 2)
void select_kernel(const float* __restrict__ survd, const int* __restrict__ survi,
                   const unsigned* __restrict__ cnt, int* __restrict__ ind,
                   unsigned* __restrict__ redoCnt, int* __restrict__ redoList) {
  const int q = blockIdx.x * 256 + threadIdx.x;
  const unsigned n = cnt[q];
  if (n > SURV_CAP) {   // dense-cluster overflow: defer to parallel redo kernels
    unsigned p = atomicAdd(redoCnt, 1u);
    redoList[p] = q;
    return;
  }
  float td[KK]; int ti[KK];
#pragma unroll
  for (int j = 0; j < KK; ++j) { td[j] = FLT_MAX; ti[j] = 0; }
  float kmax = FLT_MAX;
  for (unsigned i = 0; i < n; ++i) {
    float d = survd[(size_t)q * SURV_CAP + i];
    if (d < kmax) ins20p(td, ti, kmax, d, survi[(size_t)q * SURV_CAP + i]);
  }
#pragma unroll
  for (int j = 0; j < KK; ++j) ind[q * KK + j] = ti[j];
}

// ---------------- redo pass 1: 32 blocks per query, each scans a 512-cand slab ----
template<int C>
__global__ __launch_bounds__(256, 2)
void knn_redo_p1(const float* __restrict__ X, int ldx, const float* __restrict__ vn,
                 const int* __restrict__ redoList, const unsigned* __restrict__ redoCnt,
                 float* __restrict__ rpd, int* __restrict__ rpi) {
  __shared__ float lds_d[256 * KK];
  __shared__ int   lds_i[256 * KK];
  const int t = threadIdx.x;
  const unsigned n = *redoCnt;
  const unsigned e = blockIdx.x >> 5;
  const int part = blockIdx.x & 31;
  if (e >= n || e >= (unsigned)RQSLOTS) return;
  const int q = redoList[e];
  float qreg[C];
#pragma unroll
  for (int d = 0; d < C; ++d) qreg[d] = X[(size_t)q * ldx + d];
  float td[KK]; int ti[KK];
#pragma unroll
  for (int j = 0; j < KK; ++j) { td[j] = FLT_MAX; ti[j] = 0; }
  float kmax = FLT_MAX;
  const int cbase = part * 512;
#pragma unroll
  for (int u = 0; u < 2; ++u) {
    const int c = cbase + u * 256 + t;
    const float* crow = X + (size_t)c * ldx;
    float d0 = 0.f;
    if constexpr (C >= 4) {
      float d1 = 0.f, d2 = 0.f, d3 = 0.f;
#pragma unroll
      for (int s = 0; s < C / 4; ++s) {
        f4 cv = *(const f4*)&crow[s * 4];
        d0 = fmaf(cv[0], qreg[s * 4 + 0], d0);
        d1 = fmaf(cv[1], qreg[s * 4 + 1], d1);
        d2 = fmaf(cv[2], qreg[s * 4 + 2], d2);
        d3 = fmaf(cv[3], qreg[s * 4 + 3], d3);
      }
      d0 = (d0 + d1) + (d2 + d3);
    } else {
#pragma unroll
      for (int d = 0; d < C; ++d) d0 = fmaf(crow[d], qreg[d], d0);
    }
    float sv = fmaf(-2.f, d0, vn[c]);
    if (sv < kmax) ins20p(td, ti, kmax, sv, c);
  }
#pragma unroll
  for (int j = 0; j < KK; ++j) { lds_d[t * KK + j] = td[j]; lds_i[t * KK + j] = ti[j]; }
  __syncthreads();
  // tree merge 256 -> 64 -> 16 -> 4 -> 1 (early-break keeps sparse lists cheap)
#pragma unroll
  for (int G = 1; G <= 64; G *= 4) {
    const int nth = (G == 64) ? 1 : (G == 16) ? 4 : (G == 4) ? 16 : 64;
    if (t < nth) {
      float md[KK]; int mi[KK];
#pragma unroll
      for (int j = 0; j < KK; ++j) { md[j] = FLT_MAX; mi[j] = 0; }
      float km = FLT_MAX;
      for (int s = 0; s < 4; ++s) {
        int base = ((t * 4 + s) * G) * KK;
        for (int j = 0; j < KK; ++j) {
          float v = lds_d[base + j];
          if (v < km) ins20p(md, mi, km, v, lds_i[base + j]);
          else break;
        }
      }
      int obase = (t * 4 * G) * KK;
#pragma unroll
      for (int j = 0; j < KK; ++j) { lds_d[obase + j] = md[j]; lds_i[obase + j] = mi[j]; }
    }
    __syncthreads();
  }
  if (t == 0) {
    size_t off = ((size_t)e * 32 + part) * KK;
#pragma unroll
    for (int j = 0; j < KK; ++j) { rpd[off + j] = lds_d[j]; rpi[off + j] = lds_i[j]; }
  }
}

// ---------------- redo pass 2: one thread per query merges its 32 sorted lists ----
__global__ __launch_bounds__(256)
void knn_redo_p2(const int* __restrict__ redoList, const unsigned* __restrict__ redoCnt,
                 const float* __restrict__ rpd, const int* __restrict__ rpi,
                 int* __restrict__ ind) {
  const unsigned e = blockIdx.x * 256 + threadIdx.x;
  const unsigned n = *redoCnt;
  if (e >= n || e >= (unsigned)RQSLOTS) return;
  const int q = redoList[e];
  float td[KK]; int ti[KK];
#pragma unroll
  for (int j = 0; j < KK; ++j) { td[j] = FLT_MAX; ti[j] = 0; }
  float kmax = FLT_MAX;
  for (int p = 0; p < 32; ++p) {
    const float* dd = &rpd[((size_t)e * 32 + p) * KK];
    const int* ii = &rpi[((size_t)e * 32 + p) * KK];
    for (int j = 0; j < KK; ++j) {
      float v = dd[j];
      if (v < kmax) ins20p(td, ti, kmax, v, ii[j]);
      else break;   // lists sorted ascending
    }
  }
#pragma unroll
  for (int j = 0; j < KK; ++j) ind[q * KK + j] = ti[j];
}

// ---------------- redo fallback: whole-scan per block for e >= RQSLOTS (rare) ------
template<int C>
__global__ __launch_bounds__(256, 2)
void knn_redo_kernel(const float* __restrict__ X, int ldx, const float* __restrict__ vn,
                     const int* __restrict__ redoList, const unsigned* __restrict__ redoCnt,
                     int* __restrict__ ind, unsigned ebase) {
  __shared__ float lds_d[256 * KK];
  __shared__ int   lds_i[256 * KK];
  const int t = threadIdx.x;
  const unsigned n = *redoCnt;
  for (unsigned e = ebase + blockIdx.x; e < n; e += gridDim.x) {
    const int q = redoList[e];
    float qreg[C];
#pragma unroll
    for (int d = 0; d < C; ++d) qreg[d] = X[(size_t)q * ldx + d];
    float td[KK]; int ti[KK];
#pragma unroll
    for (int j = 0; j < KK; ++j) { td[j] = FLT_MAX; ti[j] = 0; }
    float kmax = FLT_MAX;
    for (int c = t; c < NPTS; c += 256) {
      const float* crow = X + (size_t)c * ldx;
      float d0 = 0.f;
      if constexpr (C >= 4) {
        float d1 = 0.f, d2 = 0.f, d3 = 0.f;
#pragma unroll
        for (int s = 0; s < C / 4; ++s) {
          f4 cv = *(const f4*)&crow[s * 4];
          d0 = fmaf(cv[0], qreg[s * 4 + 0], d0);
          d1 = fmaf(cv[1], qreg[s * 4 + 1], d1);
          d2 = fmaf(cv[2], qreg[s * 4 + 2], d2);
          d3 = fmaf(cv[3], qreg[s * 4 + 3], d3);
        }
        d0 = (d0 + d1) + (d2 + d3);
      } else {
#pragma unroll
        for (int d = 0; d < C; ++d) d0 = fmaf(crow[d], qreg[d], d0);
      }
      float sv = fmaf(-2.f, d0, vn[c]);
      if (sv < kmax) ins20p(td, ti, kmax, sv, c);
    }
#pragma unroll
    for (int j = 0; j < KK; ++j) { lds_d[t * KK + j] = td[j]; lds_i[t * KK + j] = ti[j]; }
    __syncthreads();
#pragma unroll
    for (int G = 1; G <= 64; G *= 4) {
      const int nth = (G == 64) ? 1 : (G == 16) ? 4 : (G == 4) ? 16 : 64;
      if (t < nth) {
        float md[KK]; int mi[KK];
#pragma unroll
        for (int j = 0; j < KK; ++j) { md[j] = FLT_MAX; mi[j] = 0; }
        float km = FLT_MAX;
        for (int s = 0; s < 4; ++s) {
          int base = ((t * 4 + s) * G) * KK;
          for (int j = 0; j < KK; ++j) {
            float v = lds_d[base + j];
            if (v < km) ins20p(md, mi, km, v, lds_i[base + j]);
            else break;
          }
        }
        int obase = (t * 4 * G) * KK;
#pragma unroll
        for (int j = 0; j < KK; ++j) { lds_d[obase + j] = md[j]; lds_i[obase + j] = mi[j]; }
      }
      __syncthreads();
    }
    if (t == 0) {
#pragma unroll
      for (int j = 0; j < KK; ++j) ind[q * KK + j] = lds_i[j];
    }
    __syncthreads();
  }
}

// ---------------- UB precompute: U = x@W1_top, B = x@(W1_bot - W1_top) ------------
template<int CIN>
__global__ __launch_bounds__(256, 2)
void ub_kernel(const float* __restrict__ X, int ldx, const float* __restrict__ W1,
               float* __restrict__ UB) {
  __shared__ __align__(16) float Ws[2 * CIN * 64];
  __shared__ __align__(16) float Xs[32][(CIN == 3) ? 4 : CIN];
  const int t = threadIdx.x;
  for (int idx = t; idx < 2 * CIN * 64; idx += 256) Ws[idx] = W1[idx];
  const int pb = blockIdx.x * 32;
  if constexpr (CIN == 64) {
    int r = t >> 3, g = t & 7;
    f4 a = *(const f4*)&X[(size_t)(pb + r) * ldx + g * 8];
    f4 b = *(const f4*)&X[(size_t)(pb + r) * ldx + g * 8 + 4];
    *(f4*)&Xs[r][g * 8] = a;
    *(f4*)&Xs[r][g * 8 + 4] = b;
  } else {
    if (t < 32 * CIN) {
      int r = t / CIN, d = t - r * CIN;
      Xs[r][d] = X[(size_t)(pb + r) * ldx + d];
    }
  }
  __syncthreads();
  const int p = t >> 3, c0 = (t & 7) * 8;
  float u[8], v[8];
#pragma unroll
  for (int e = 0; e < 8; ++e) { u[e] = 0.f; v[e] = 0.f; }
#pragma unroll 4
  for (int k = 0; k < CIN; ++k) {
    float xv = Xs[p][k];
    f4 wt0 = *(const f4*)&Ws[k * 64 + c0];
    f4 wt1 = *(const f4*)&Ws[k * 64 + c0 + 4];
    f4 wb0 = *(const f4*)&Ws[(CIN + k) * 64 + c0];
    f4 wb1 = *(const f4*)&Ws[(CIN + k) * 64 + c0 + 4];
#pragma unroll
    for (int e = 0; e < 4; ++e) {
      u[e]     = fmaf(xv, wt0[e], u[e]);
      u[4 + e] = fmaf(xv, wt1[e], u[4 + e]);
      v[e]     = fmaf(xv, wb0[e], v[e]);
      v[4 + e] = fmaf(xv, wb1[e], v[4 + e]);
    }
  }
  float* o = &UB[(size_t)(pb + p) * 128];
  f4 a0 = {u[0], u[1], u[2], u[3]}, a1 = {u[4], u[5], u[6], u[7]};
  f4 b0 = {v[0] - u[0], v[1] - u[1], v[2] - u[2], v[3] - u[3]};
  f4 b1 = {v[4] - u[4], v[5] - u[5], v[6] - u[6], v[7] - u[7]};
  *(f4*)&o[c0] = a0;       *(f4*)&o[c0 + 4] = a1;
  *(f4*)&o[64 + c0] = b0;  *(f4*)&o[64 + c0 + 4] = b1;
}

// ---------------- edgeconv TWO-layer: h1 = prelu(U[nb]+B[i]); out = max prelu(h1@W2)
__global__ __launch_bounds__(256, 3)
void edgeconv2_kernel(const float* __restrict__ UB, const int* __restrict__ ind,
                      const float* __restrict__ W2, const float* __restrict__ p1p,
                      const float* __restrict__ p2p,
                      float* __restrict__ Y, int ldy) {
  __shared__ __align__(16) float W2s[64 * 64];     // 16 KB
  __shared__ __align__(16) float h1[4][64 * 32];   // 32 KB, [c][kslot]
  __shared__ float Bs[4][64];
  __shared__ int nbs[4][KK];
  const int t = threadIdx.x;
  const int w = t >> 6, l = t & 63;
  const float a1 = *p1p, a2 = *p2p;
  const int i = blockIdx.x * 4 + w;
  for (int idx = t; idx < 64 * 64; idx += 256) W2s[idx] = W2[idx];
  if (l < 16) *(f4*)&Bs[w][l * 4] = *(const f4*)&UB[(size_t)i * 128 + 64 + l * 4];
  if (l < KK) nbs[w][l] = ind[i * KK + l];
  __syncthreads();

  {  // build h1 for this warp's point: lane -> (kslot, channel half)
    const int kslot = l >> 1, ch0 = (l & 1) * 32;
    if (kslot < KK) {
      const int nb = nbs[w][kslot];
      const float* ur = &UB[(size_t)nb * 128 + ch0];
#pragma unroll
      for (int g = 0; g < 8; ++g) {
        f4 uv = *(const f4*)&ur[g * 4];
#pragma unroll
        for (int e = 0; e < 4; ++e) {
          int c = ch0 + g * 4 + e;
          float hv = uv[e] + Bs[w][c];
          hv = fmaxf(hv, 0.f) + a1 * fminf(hv, 0.f);
          h1[w][c * 32 + kslot] = hv;
        }
      }
    } else {
#pragma unroll
      for (int g = 0; g < 32; ++g) h1[w][(ch0 + g) * 32 + kslot] = 0.f;
    }
  }
  __syncthreads();

  // GEMM2: lane = kg*8+cg, tile 4nb x 8ch over padded 32 neighbors
  const int kg = l >> 3, cg = l & 7;
  const int k0 = kg * 4, c0 = cg * 8;
  float acc[4][8];
#pragma unroll
  for (int a = 0; a < 4; ++a)
#pragma unroll
    for (int b = 0; b < 8; ++b) acc[a][b] = 0.f;
#pragma unroll 4
  for (int c = 0; c < 64; ++c) {
    f4 hv = *(const f4*)&h1[w][c * 32 + k0];
    f4 w0 = *(const f4*)&W2s[c * 64 + c0];
    f4 w1 = *(const f4*)&W2s[c * 64 + c0 + 4];
    float wr[8] = {w0[0], w0[1], w0[2], w0[3], w1[0], w1[1], w1[2], w1[3]};
#pragma unroll
    for (int a = 0; a < 4; ++a)
#pragma unroll
      for (int b = 0; b < 8; ++b)
        acc[a][b] = fmaf(hv[a], wr[b], acc[a][b]);
  }

  // prelu + masked max (20 = 5 full groups of 4; kg>=5 are pad)
  float mx[8];
#pragma unroll
  for (int b = 0; b < 8; ++b) mx[b] = -FLT_MAX;
  if (kg < 5) {
#pragma unroll
    for (int a = 0; a < 4; ++a)
#pragma unroll
      for (int b = 0; b < 8; ++b) {
        float v = fmaxf(acc[a][b], 0.f) + a2 * fminf(acc[a][b], 0.f);
        mx[b] = fmaxf(mx[b], v);
      }
  }
#pragma unroll
  for (int b = 0; b < 8; ++b) {
    mx[b] = fmaxf(mx[b], __shfl_xor(mx[b], 8));
    mx[b] = fmaxf(mx[b], __shfl_xor(mx[b], 16));
    mx[b] = fmaxf(mx[b], __shfl_xor(mx[b], 32));
  }
  if (kg == 0) {
    f4 o0 = {mx[0], mx[1], mx[2], mx[3]}, o1 = {mx[4], mx[5], mx[6], mx[7]};
    float* yp = &Y[(size_t)i * ldy + c0];
    *(f4*)yp = o0;
    *(f4*)(yp + 4) = o1;
  }
}

// ---------------- edgeconv ONE-layer: out[i][c] = max_k prelu(U[nb][c]+B[i][c]) ----
__global__ __launch_bounds__(256, 4)
void edgeconv1_kernel(const float* __restrict__ UB, const int* __restrict__ ind,
                      const float* __restrict__ p1p, float* __restrict__ Y, int ldy) {
  __shared__ int nbs[4][KK];
  __shared__ float Bs[4][64];
  const int t = threadIdx.x;
  const int w = t >> 6, l = t & 63;
  const float a1 = *p1p;
  const int i = blockIdx.x * 4 + w;
  if (l < KK) nbs[w][l] = ind[i * KK + l];
  if (l < 16) *(f4*)&Bs[w][l * 4] = *(const f4*)&UB[(size_t)i * 128 + 64 + l * 4];
  __syncthreads();
  const float b = Bs[w][l];
  float mx = -FLT_MAX;
#pragma unroll 4
  for (int k = 0; k < KK; ++k) {
    float uv = UB[(size_t)nbs[w][k] * 128 + l];
    float hv = uv + b;
    hv = fmaxf(hv, 0.f) + a1 * fminf(hv, 0.f);
    mx = fmaxf(mx, hv);
  }
  Y[(size_t)i * ldy + l] = mx;
}

// ---------------- ordered-float encode for atomicMax ----------------
__device__ __forceinline__ unsigned fenc(float f) {
  unsigned u = __float_as_uint(f);
  return (u & 0x80000000u) ? ~u : (u | 0x80000000u);
}
__device__ __forceinline__ float fdec(unsigned u) {
  return (u & 0x80000000u) ? __uint_as_float(u & 0x7fffffffu) : __uint_as_float(~u);
}

__global__ void initg_kernel(unsigned* __restrict__ g) {
  g[blockIdx.x * 256 + threadIdx.x] = 0x007FFFFFu;  // fenc(-inf)
}

// ---------------- split fp32 -> (hi, lo) bf16, flat over n8 groups of 8 ----------
__global__ __launch_bounds__(256)
void splitA_kernel(const float* __restrict__ X, int n8,
                   short* __restrict__ hi, short* __restrict__ lo) {
  int idx = blockIdx.x * 256 + threadIdx.x;
  if (idx >= n8) return;
  f4 a = *(const f4*)&X[(size_t)idx * 8];
  f4 b = *(const f4*)&X[(size_t)idx * 8 + 4];
  bh8 h, w;
#pragma unroll
  for (int e = 0; e < 4; ++e) {
    float v0 = a[e], v1 = b[e];
    __hip_bfloat16 h0 = __float2bfloat16(v0);
    __hip_bfloat16 h1 = __float2bfloat16(v1);
    __hip_bfloat16 l0 = __float2bfloat16(v0 - __bfloat162float(h0));
    __hip_bfloat16 l1 = __float2bfloat16(v1 - __bfloat162float(h1));
    h[e] = *reinterpret_cast<short*>(&h0); h[4 + e] = *reinterpret_cast<short*>(&h1);
    w[e] = *reinterpret_cast<short*>(&l0); w[4 + e] = *reinterpret_cast<short*>(&l1);
  }
  *(bh8*)&hi[(size_t)idx * 8] = h;
  *(bh8*)&lo[(size_t)idx * 8] = w;
}

// ---------------- split + transpose W [K,ldw] -> Wt hi/lo [M][K] bf16 -------------
__global__ __launch_bounds__(256)
void splitWt_kernel(const float* __restrict__ W, int ldw, int M, int K,
                    short* __restrict__ hi, short* __restrict__ lo) {
  int idx = blockIdx.x * 256 + threadIdx.x;   // (c, kgroup8)
  int kg8 = K / 8;
  if (idx >= M * kg8) return;
  int c = idx / kg8, kg = idx - c * kg8;
  bh8 h, w;
#pragma unroll
  for (int e = 0; e < 8; ++e) {
    float v = W[(size_t)(kg * 8 + e) * ldw + c];
    __hip_bfloat16 hv = __float2bfloat16(v);
    __hip_bfloat16 lv = __float2bfloat16(v - __bfloat162float(hv));
    h[e] = *reinterpret_cast<short*>(&hv);
    w[e] = *reinterpret_cast<short*>(&lv);
  }
  *(bh8*)&hi[(size_t)c * K + kg * 8] = h;
  *(bh8*)&lo[(size_t)c * K + kg * 8] = w;
}

// ---------------- split-bf16 MFMA GEMM + prelu; MODE 1: colmax, MODE 2: bias+store -
template<int MODE, int K>
__global__ __launch_bounds__(256, 2)
void gemm_mfma_kernel(const short* __restrict__ Ahi, const short* __restrict__ Alo,
                      const short* __restrict__ Wthi, const short* __restrict__ Wtlo,
                      const float* __restrict__ bias, const float* __restrict__ pptr,
                      float* __restrict__ Cm, int ldc, unsigned* __restrict__ gmax) {
  __shared__ __align__(16) short Ah[128 * 32], Al[128 * 32];
  __shared__ __align__(16) short Bh[128 * 32], Bl[128 * 32];   // 32 KB total
  const int t = threadIdx.x;
  const int rb = blockIdx.x * 128, cb = blockIdx.y * 128;
  const float aa = *pptr;
  const int w = t >> 6, l = t & 63;
  const int rsub = (w >> 1) * 64, csub = (w & 1) * 64;
  const int lr = l & 15, lh = l >> 4;

  f32x4 acc[4][4];
#pragma unroll
  for (int i = 0; i < 4; ++i)
#pragma unroll
    for (int j = 0; j < 4; ++j) acc[i][j] = f32x4{0.f, 0.f, 0.f, 0.f};

  for (int ck = 0; ck < K; ck += 32) {
    __syncthreads();
#pragma unroll
    for (int u = 0; u < 2; ++u) {
      int idx = u * 256 + t;          // 0..511 = 128 rows x 4 slots
      int row = idx >> 2, s = idx & 3;
      int ssw = s ^ (row & 3);
      *(bh8*)&Ah[row * 32 + ssw * 8] = *(const bh8*)&Ahi[(size_t)(rb + row) * K + ck + s * 8];
      *(bh8*)&Al[row * 32 + ssw * 8] = *(const bh8*)&Alo[(size_t)(rb + row) * K + ck + s * 8];
      *(bh8*)&Bh[row * 32 + ssw * 8] = *(const bh8*)&Wthi[(size_t)(cb + row) * K + ck + s * 8];
      *(bh8*)&Bl[row * 32 + ssw * 8] = *(const bh8*)&Wtlo[(size_t)(cb + row) * K + ck + s * 8];
    }
    __syncthreads();
    bh8 ah[4], al[4], bh_[4], bl_[4];
#pragma unroll
    for (int i = 0; i < 4; ++i) {
      int r = rsub + i * 16 + lr;
      int ssw = lh ^ (r & 3);
      ah[i] = *(const bh8*)&Ah[r * 32 + ssw * 8];
      al[i] = *(const bh8*)&Al[r * 32 + ssw * 8];
      int c = csub + i * 16 + lr;
      int csw = lh ^ (c & 3);
      bh_[i] = *(const bh8*)&Bh[c * 32 + csw * 8];
      bl_[i] = *(const bh8*)&Bl[c * 32 + csw * 8];
    }
#pragma unroll
    for (int i = 0; i < 4; ++i)
#pragma unroll
      for (int j = 0; j < 4; ++j) {
        acc[i][j] = __builtin_amdgcn_mfma_f32_16x16x32_bf16(ah[i], bh_[j], acc[i][j], 0, 0, 0);
        acc[i][j] = __builtin_amdgcn_mfma_f32_16x16x32_bf16(ah[i], bl_[j], acc[i][j], 0, 0, 0);
        acc[i][j] = __builtin_amdgcn_mfma_f32_16x16x32_bf16(al[i], bh_[j], acc[i][j], 0, 0, 0);
      }
  }

  if (MODE == 1) {   // prelu + column max -> gmax (fenc atomic)
    float cmax[4];
#pragma unroll
    for (int j = 0; j < 4; ++j) cmax[j] = -FLT_MAX;
#pragma unroll
    for (int i = 0; i < 4; ++i)
#pragma unroll
      for (int r = 0; r < 4; ++r)
#pragma unroll
        for (int j = 0; j < 4; ++j) {
          float v = acc[i][j][r];
          v = fmaxf(v, 0.f) + aa * fminf(v, 0.f);
          cmax[j] = fmaxf(cmax[j], v);
        }
#pragma unroll
    for (int j = 0; j < 4; ++j) {
      cmax[j] = fmaxf(cmax[j], __shfl_xor(cmax[j], 16));
      cmax[j] = fmaxf(cmax[j], __shfl_xor(cmax[j], 32));
    }
    if (l < 16) {
#pragma unroll
      for (int j = 0; j < 4; ++j)
        atomicMax(&gmax[cb + csub + j * 16 + l], fenc(cmax[j]));
    }
  } else {           // bias + prelu + store
#pragma unroll
    for (int i = 0; i < 4; ++i)
#pragma unroll
      for (int r = 0; r < 4; ++r) {
        const int row = rsub + i * 16 + lh * 4 + r;
#pragma unroll
        for (int j = 0; j < 4; ++j) {
          const int col = csub + j * 16 + lr;
          float v = acc[i][j][r] + bias[cb + col];
          v = fmaxf(v, 0.f) + aa * fminf(v, 0.f);
          Cm[(size_t)(rb + row) * ldc + cb + col] = v;
        }
      }
  }
}

// ---------------- generic fp32 GEMM + prelu; MODE: 0 store, 1 colmax, 2 bias+store ----
template<int MODE>
__global__ __launch_bounds__(256, 2)
void gemm_kernel(const float* __restrict__ A, int lda,
                 const float* __restrict__ W, int ldw,
                 const float* __restrict__ bias,
                 const float* __restrict__ pptr,
                 float* __restrict__ Cm, int ldc, int Ktot,
                 unsigned* __restrict__ gmax) {
  __shared__ __align__(16) float At[16 * 132];
  __shared__ __align__(16) float Ws[16 * 128];
  const int t = threadIdx.x;
  const int rb = blockIdx.x * 128, cbb = blockIdx.y * 128;
  const int r0 = (t & 15) * 8, c0 = (t >> 4) * 8;
  const float aa = *pptr;

  float acc[8][8];
#pragma unroll
  for (int i = 0; i < 8; ++i)
#pragma unroll
    for (int j = 0; j < 8; ++j) acc[i][j] = 0.f;

  const int sr = t >> 1, skh = (t & 1) * 8;
  const int wk = t >> 4, wc = (t & 15) * 8;

  for (int k0 = 0; k0 < Ktot; k0 += 16) {
    __syncthreads();
    {
      const float* ap = &A[(size_t)(rb + sr) * lda + k0 + skh];
      f4 v0 = *(const f4*)ap;
      f4 v1 = *(const f4*)(ap + 4);
#pragma unroll
      for (int e = 0; e < 4; ++e) {
        At[(skh + e) * 132 + sr] = v0[e];
        At[(skh + 4 + e) * 132 + sr] = v1[e];
      }
      const float* wp = &W[(size_t)(k0 + wk) * ldw + cbb + wc];
      *(f4*)&Ws[wk * 128 + wc] = *(const f4*)wp;
      *(f4*)&Ws[wk * 128 + wc + 4] = *(const f4*)(wp + 4);
    }
    __syncthreads();
#pragma unroll 4
    for (int d = 0; d < 16; ++d) {
      f4 qa = *(const f4*)&At[d * 132 + r0];
      f4 qb = *(const f4*)&At[d * 132 + r0 + 4];
      f4 wa = *(const f4*)&Ws[d * 128 + c0];
      f4 wb = *(const f4*)&Ws[d * 128 + c0 + 4];
      float qr[8] = {qa[0], qa[1], qa[2], qa[3], qb[0], qb[1], qb[2], qb[3]};
      float wr[8] = {wa[0], wa[1], wa[2], wa[3], wb[0], wb[1], wb[2], wb[3]};
#pragma unroll
      for (int i = 0; i < 8; ++i)
#pragma unroll
        for (int j = 0; j < 8; ++j)
          acc[i][j] = fmaf(qr[i], wr[j], acc[i][j]);
    }
  }

  float bv[8];
#pragma unroll
  for (int j = 0; j < 8; ++j) bv[j] = (MODE == 2) ? bias[cbb + c0 + j] : 0.f;
#pragma unroll
  for (int i = 0; i < 8; ++i)
#pragma unroll
    for (int j = 0; j < 8; ++j) {
      float v = acc[i][j] + bv[j];
      acc[i][j] = fmaxf(v, 0.f) + aa * fminf(v, 0.f);
    }

  if (MODE == 1) {
    float cmax[8];
#pragma unroll
    for (int j = 0; j < 8; ++j) {
      cmax[j] = acc[0][j];
#pragma unroll
      for (int i = 1; i < 8; ++i) cmax[j] = fmaxf(cmax[j], acc[i][j]);
    }
    __syncthreads();
#pragma unroll
    for (int j = 0; j < 8; ++j) At[(t & 15) * 132 + c0 + j] = cmax[j];
    __syncthreads();
    if (t < 128) {
      float m = At[t];
      for (int rr = 1; rr < 16; ++rr) m = fmaxf(m, At[rr * 132 + t]);
      atomicMax(&gmax[cbb + t], fenc(m));
    }
  } else {
#pragma unroll
    for (int i = 0; i < 8; ++i) {
      f4 s0 = {acc[i][0], acc[i][1], acc[i][2], acc[i][3]};
      f4 s1 = {acc[i][4], acc[i][5], acc[i][6], acc[i][7]};
      float* cp = &Cm[(size_t)(rb + r0 + i) * ldc + cbb + c0];
      *(f4*)cp = s0;
      *(f4*)(cp + 4) = s1;
    }
  }
}

// ---------------- bias5[c] = sum_j g[j] * W5[192+j][c] ----------------
__global__ void bias5_kernel(const unsigned* __restrict__ gmax, const float* __restrict__ W5,
                             float* __restrict__ bias5) {
  __shared__ float gs[1024];
  __shared__ float pm[4 * 256];
  int t = threadIdx.x;  // 1024 threads
  gs[t] = fdec(gmax[t]);
  __syncthreads();
  int c = t & 255, p = t >> 8;
  float acc = 0.f;
  for (int j = p * 256; j < p * 256 + 256; ++j)
    acc = fmaf(gs[j], W5[(size_t)(192 + j) * 256 + c], acc);
  pm[p * 256 + c] = acc;
  __syncthreads();
  if (t < 256) bias5[t] = pm[t] + pm[256 + t] + pm[512 + t] + pm[768 + t];
}

// ---------------- final [N,128]@[128,3] + prelu + hidden passthrough ----------------
__global__ __launch_bounds__(256, 2)
void w8_kernel(const float* __restrict__ A, const float* __restrict__ W8,
               const float* __restrict__ pptr, const float* __restrict__ hidden,
               float* __restrict__ out) {
  __shared__ __align__(16) float As[64 * 132];
  __shared__ float W8s[128 * COUT];
  int t = threadIdx.x;
  int rb = blockIdx.x * 64;
  for (int idx = t; idx < 128 * COUT; idx += 256) W8s[idx] = W8[idx];
  for (int idx = t; idx < 64 * 32; idx += 256) {
    int r = idx >> 5, c4 = idx & 31;
    *(f4*)&As[r * 132 + c4 * 4] = *(const f4*)&A[(size_t)(rb + r) * 128 + c4 * 4];
  }
  const float a = *pptr;
  __syncthreads();
  int r = t >> 2, c = t & 3;
  if (c < COUT) {
    float acc = 0.f;
#pragma unroll 8
    for (int j = 0; j < 128; ++j)
      acc = fmaf(As[r * 132 + j], W8s[j * COUT + c], acc);
    float v = fmaxf(acc, 0.f) + a * fminf(acc, 0.f);
    out[(size_t)(rb + r) * COUT + c] = v;
  }
  if (blockIdx.x == 0 && t == 0) out[(size_t)NPTS * COUT] = hidden[0];
}

// ---------------- host launch ----------------
extern "C" void kernel_launch(void* const* d_in, const int* in_sizes, int n_in,
                              void* d_out, int out_size, void* d_ws, size_t ws_size,
                              hipStream_t stream) {
  (void)in_sizes; (void)n_in; (void)out_size; (void)ws_size;
  const float* x      = (const float*)d_in[0];
  const float* hidden = (const float*)d_in[1];
  const float* W1a = (const float*)d_in[2];
  const float* p1a = (const float*)d_in[3];
  const float* W1b = (const float*)d_in[4];
  const float* p1b = (const float*)d_in[5];
  const float* W2a = (const float*)d_in[6];
  const float* p2a = (const float*)d_in[7];
  const float* W2b = (const float*)d_in[8];
  const float* p2b = (const float*)d_in[9];
  const float* W3  = (const float*)d_in[10];
  const float* p3  = (const float*)d_in[11];
  const float* W4  = (const float*)d_in[12];
  const float* p4  = (const float*)d_in[13];
  const float* W5  = (const float*)d_in[14];
  const float* p5  = (const float*)d_in[15];
  const float* W6  = (const float*)d_in[16];
  const float* p6  = (const float*)d_in[17];
  const float* W7  = (const float*)d_in[18];
  const float* p7  = (const float*)d_in[19];
  const float* W8  = (const float*)d_in[20];
  const float* p8  = (const float*)d_in[21];
  float* out = (float*)d_out;

  char* ws = (char*)d_ws;
  size_t off = 0;
  auto carve = [&](size_t bytes) -> void* {
    void* p = ws + off;
    off = (off + bytes + 255) & ~(size_t)255;
    return p;
  };
  float*    x4    = (float*)   carve((size_t)NPTS * 192 * 4);  // [x1|x2|x3], ld=192 (reused as h7)
  float*    vn    = (float*)   carve((size_t)NPTS * 4);
  float*    sn    = (float*)   carve((size_t)NPTS * 4);
  int*      ind   = (int*)     carve((size_t)NPTS * KK * 4);
  float*    T     = (float*)   carve((size_t)NPTS * 4);
  unsigned* cnt   = (unsigned*)carve((size_t)NPTS * 4);
  unsigned* redoCnt = (unsigned*)carve(256);
  int*      redoList = (int*)  carve((size_t)NPTS * 4);
  float*    rpd   = (float*)   carve((size_t)RQSLOTS * 32 * KK * 4);  // redo pass1 lists
  int*      rpi   = (int*)     carve((size_t)RQSLOTS * 32 * KK * 4);
  float*    meanb = (float*)   carve(64 * 4);
  float*    Xc    = (float*)   carve((size_t)NPTS * 64 * 4);   // centered fp32 slice
  short*    Xbf   = (short*)   carve((size_t)NPTS * 64 * 2);   // centered bf16 slice
  float*    plist = (float*)   carve((size_t)2 * NPTS * 64 * 4); // sampler lists; reused as UB
  short*    Ahi   = (short*)   carve((size_t)NPTS * 192 * 2);  // x4 split hi
  short*    Alo   = (short*)   carve((size_t)NPTS * 192 * 2);  // x4 split lo
  short*    Wt4h  = (short*)   carve((size_t)1024 * 192 * 2);
  short*    Wt4l  = (short*)   carve((size_t)1024 * 192 * 2);
  short*    Wt5h  = (short*)   carve((size_t)256 * 192 * 2);
  short*    Wt5l  = (short*)   carve((size_t)256 * 192 * 2);
  unsigned* gmax  = (unsigned*)carve(1024 * 4);
  float*    bias5 = (float*)   carve(256 * 4);
  float*    h5    = (float*)   carve((size_t)NPTS * 256 * 4);  // aliased: survd (knn phase)
  float*    h6    = (float*)   carve((size_t)NPTS * 256 * 4);  // aliased: survi (knn phase)
  float* survd = h5;
  int*   survi = (int*)h6;
  float* h7 = x4;   // x4 dead after W5 GEMM
  float* UB = plist; // plist dead after mergeT; UB = [N][128] (U|B), same size

  // ---- stage 1: knn(x, C=3, reg-query filter) + edgeconv1 -> x4[:, 0:64] ----
  norms_kernel<3><<<64, 256, 0, stream>>>(x, 3, vn);
  sampleTv4_kernel<3><<<dim3(256, 2), 256, 0, stream>>>(x, vn, plist);
  mergeT_kernel<<<64, 256, 0, stream>>>(plist, T, cnt, redoCnt);
  knn_filter3_kernel<<<dim3(128, 8), 256, 0, stream>>>(x, vn, T, survd, survi, cnt);
  select_kernel<<<64, 256, 0, stream>>>(survd, survi, cnt, ind, redoCnt, redoList);
  knn_redo_p1<3><<<RQSLOTS * 32, 256, 0, stream>>>(x, 3, vn, redoList, redoCnt, rpd, rpi);
  knn_redo_p2<<<1, 256, 0, stream>>>(redoList, redoCnt, rpd, rpi, ind);
  knn_redo_kernel<3><<<256, 256, 0, stream>>>(x, 3, vn, redoList, redoCnt, ind, RQSLOTS);
  ub_kernel<3><<<512, 256, 0, stream>>>(x, 3, W1a, UB);
  edgeconv2_kernel<<<4096, 256, 0, stream>>>(UB, ind, W1b, p1a, p1b, x4 + 0, 192);

  // ---- stage 2: knn(x1 centered, MFMA filter) + edgeconv2 -> x4[:, 64:128] ----
  mean64_kernel<<<64, 256, 0, stream>>>(x4 + 0, 192, meanb);
  xc_kernel<<<512, 256, 0, stream>>>(x4 + 0, 192, meanb, Xc, Xbf, vn, sn);
  sampleTv4_kernel<64><<<dim3(256, 2), 256, 0, stream>>>(Xc, vn, plist);
  mergeT_kernel<<<64, 256, 0, stream>>>(plist, T, cnt, redoCnt);
  knn_filter64_mfma<<<dim3(128, 128), 256, 0, stream>>>(Xbf, vn, sn, T, survi, cnt);
  exact_kernel<64><<<NPTS, 256, 0, stream>>>(Xc, 64, vn, cnt, survi, survd);
  select_kernel<<<64, 256, 0, stream>>>(survd, survi, cnt, ind, redoCnt, redoList);
  knn_redo_p1<64><<<RQSLOTS * 32, 256, 0, stream>>>(Xc, 64, vn, redoList, redoCnt, rpd, rpi);
  knn_redo_p2<<<1, 256, 0, stream>>>(redoList, redoCnt, rpd, rpi, ind);
  knn_redo_kernel<64><<<256, 256, 0, stream>>>(Xc, 64, vn, redoList, redoCnt, ind, RQSLOTS);
  ub_kernel<64><<<512, 256, 0, stream>>>(x4 + 0, 192, W2a, UB);
  edgeconv2_kernel<<<4096, 256, 0, stream>>>(UB, ind, W2b, p2a, p2b, x4 + 64, 192);

  // ---- stage 3: knn(x2 centered, MFMA filter) + edgeconv3 -> x4[:, 128:192] ----
  mean64_kernel<<<64, 256, 0, stream>>>(x4 + 64, 192, meanb);
  xc_kernel<<<512, 256, 0, stream>>>(x4 + 64, 192, meanb, Xc, Xbf, vn, sn);
  sampleTv4_kernel<64><<<dim3(256, 2), 256, 0, stream>>>(Xc, vn, plist);
  mergeT_kernel<<<64, 256, 0, stream>>>(plist, T, cnt, redoCnt);
  knn_filter64_mfma<<<dim3(128, 128), 256, 0, stream>>>(Xbf, vn, sn, T, survi, cnt);
  exact_kernel<64><<<NPTS, 256, 0, stream>>>(Xc, 64, vn, cnt, survi, survd);
  select_kernel<<<64, 256, 0, stream>>>(survd, survi, cnt, ind, redoCnt, redoList);
  knn_redo_p1<64><<<RQSLOTS * 32, 256, 0, stream>>>(Xc, 64, vn, redoList, redoCnt, rpd, rpi);
  knn_redo_p2<<<1, 256, 0, stream>>>(redoList, redoCnt, rpd, rpi, ind);
  knn_redo_kernel<64><<<256, 256, 0, stream>>>(Xc, 64, vn, redoList, redoCnt, ind, RQSLOTS);
  ub_kernel<64><<<512, 256, 0, stream>>>(x4 + 64, 192, W3, UB);
  edgeconv1_kernel<<<4096, 256, 0, stream>>>(UB, ind, p3, x4 + 128, 192);

  // ---- split x4 / W4 / W5 into bf16 hi+lo for MFMA tail ----
  splitA_kernel<<<(NPTS * 192 / 8 + 255) / 256, 256, 0, stream>>>(x4, NPTS * 192 / 8, Ahi, Alo);
  splitWt_kernel<<<(1024 * 24 + 255) / 256, 256, 0, stream>>>(W4, 1024, 1024, 192, Wt4h, Wt4l);
  splitWt_kernel<<<(256 * 24 + 255) / 256, 256, 0, stream>>>(W5, 256, 256, 192, Wt5h, Wt5l);

  // ---- x5 = prelu(x4@W4); g = colmax(x5)  [split-bf16 MFMA] ----
  initg_kernel<<<4, 256, 0, stream>>>(gmax);
  gemm_mfma_kernel<1, 192><<<dim3(128, 8), 256, 0, stream>>>(Ahi, Alo, Wt4h, Wt4l, nullptr, p4, nullptr, 0, gmax);

  // ---- bias5 = g @ W5[192:1216] ----
  bias5_kernel<<<1, 1024, 0, stream>>>(gmax, W5, bias5);

  // ---- h5 = prelu(x4@W5[0:192] + bias5)  [split-bf16 MFMA] ----
  gemm_mfma_kernel<2, 192><<<dim3(128, 2), 256, 0, stream>>>(Ahi, Alo, Wt5h, Wt5l, bias5, p5, h5, 256, nullptr);
  // ---- h6 = prelu(h5@W6) ----
  gemm_kernel<0><<<dim3(128, 2), 256, 0, stream>>>(h5, 256, W6, 256, nullptr, p6, h6, 256, 256, nullptr);
  // ---- h7 = prelu(h6@W7) ----
  gemm_kernel<0><<<dim3(128, 1), 256, 0, stream>>>(h6, 256, W7, 128, nullptr, p7, h7, 128, 256, nullptr);
  // ---- out = prelu(h7@W8); out[N*3] = hidden ----
  w8_kernel<<<256, 256, 0, stream>>>(h7, W8, p8, hidden, out);
}

// Round 20
// 1731.235 us; speedup vs baseline: 1.1445x; 1.0530x over previous
//
#include <hip/hip_runtime.h>
#include <hip/hip_bf16.h>
#include <float.h>

#define NPTS 16384
#define KK 20
#define COUT 3
#define SURV_CAP 256
#define RQSLOTS 256

typedef float f4 __attribute__((ext_vector_type(4)));
typedef float f32x4 __attribute__((ext_vector_type(4)));
typedef short bh8 __attribute__((ext_vector_type(8)));   // 8 bf16 in 4 VGPRs

// ---------------- sorted top-20 insert, values only ----------------
__device__ __forceinline__ void ins20(float (&td)[KK], float &kmax, float nd) {
  float cd = nd;
#pragma unroll
  for (int j = 0; j < KK; ++j) {
    float t0 = td[j];
    bool lt = cd < t0;
    td[j] = lt ? cd : t0;
    cd = lt ? t0 : cd;
  }
  kmax = td[KK - 1];
}

// ---------------- sorted top-4 insert, values only ----------------
__device__ __forceinline__ void ins4(float (&td)[4], float &kmax, float nd) {
  float cd = nd;
#pragma unroll
  for (int j = 0; j < 4; ++j) {
    float t0 = td[j];
    bool lt = cd < t0;
    td[j] = lt ? cd : t0;
    cd = lt ? t0 : cd;
  }
  kmax = td[3];
}

// ---------------- sorted top-20 insert, (value, index) ----------------
__device__ __forceinline__ void ins20p(float (&td)[KK], int (&ti)[KK],
                                       float &kmax, float nd, int ni) {
  float cd = nd; int ci = ni;
#pragma unroll
  for (int j = 0; j < KK; ++j) {
    float t0 = td[j]; int t1 = ti[j];
    bool lt = cd < t0;
    td[j] = lt ? cd : t0;  ti[j] = lt ? ci : t1;
    cd = lt ? t0 : cd;     ci = lt ? t1 : ci;
  }
  kmax = td[KK - 1];
}

// ---------------- row squared norms (stage-1 / C=3 path) ----------------
template<int C>
__global__ void norms_kernel(const float* __restrict__ X, int ldx, float* __restrict__ vn) {
  int i = blockIdx.x * 256 + threadIdx.x;
  if (i >= NPTS) return;
  const float* row = X + (size_t)i * ldx;
  float s = 0.f;
#pragma unroll
  for (int c = 0; c < C; ++c) s = fmaf(row[c], row[c], s);
  vn[i] = s;
}

// ---------------- deterministic column mean over 64 dims ----------------
__global__ __launch_bounds__(256)
void mean64_kernel(const float* __restrict__ X, int ldx, float* __restrict__ mean) {
  __shared__ float p[256];
  const int d = blockIdx.x, t = threadIdx.x;
  float s = 0.f;
  for (int r = t; r < NPTS; r += 256) s += X[(size_t)r * ldx + d];
  p[t] = s;
  __syncthreads();
  for (int o = 128; o > 0; o >>= 1) { if (t < o) p[t] += p[t + o]; __syncthreads(); }
  if (t == 0) mean[d] = p[0] * (1.0f / NPTS);
}

// ---------------- center + fp32 copy + bf16 copy + vn + sn  (64-dim slice) --------
__global__ __launch_bounds__(256)
void xc_kernel(const float* __restrict__ X, int ldx, const float* __restrict__ mean,
               float* __restrict__ Xc, short* __restrict__ Xbf,
               float* __restrict__ vn, float* __restrict__ sn) {
  __shared__ float msh[64];
  const int t = threadIdx.x;
  if (t < 64) msh[t] = mean[t];
  __syncthreads();
  const int row = blockIdx.x * 32 + (t >> 3), sub = t & 7;
  f4 a = *(const f4*)&X[(size_t)row * ldx + sub * 8];
  f4 b = *(const f4*)&X[(size_t)row * ldx + sub * 8 + 4];
#pragma unroll
  for (int e = 0; e < 4; ++e) { a[e] -= msh[sub * 8 + e]; b[e] -= msh[sub * 8 + 4 + e]; }
  *(f4*)&Xc[(size_t)row * 64 + sub * 8] = a;
  *(f4*)&Xc[(size_t)row * 64 + sub * 8 + 4] = b;
  bh8 o;
#pragma unroll
  for (int e = 0; e < 4; ++e) {
    __hip_bfloat16 ha = __float2bfloat16(a[e]);
    __hip_bfloat16 hb = __float2bfloat16(b[e]);
    o[e] = *reinterpret_cast<short*>(&ha);
    o[4 + e] = *reinterpret_cast<short*>(&hb);
  }
  *(bh8*)&Xbf[(size_t)row * 64 + sub * 8] = o;
  float s = a[0]*a[0] + a[1]*a[1] + a[2]*a[2] + a[3]*a[3]
          + b[0]*b[0] + b[1]*b[1] + b[2]*b[2] + b[3]*b[3];
  s += __shfl_xor(s, 1);
  s += __shfl_xor(s, 2);
  s += __shfl_xor(s, 4);
  if (sub == 0) { vn[row] = s; sn[row] = sqrtf(s); }
}

// ---------------- phase S v4: tiled sampler -> per-thread top-4 lists -------------
template<int C>
__global__ __launch_bounds__(256, 2)
void sampleTv4_kernel(const float* __restrict__ X, const float* __restrict__ vn,
                      float* __restrict__ plist) {
  __shared__ __align__(16) float Qs[C * 64];     // dim-major [d][q]
  __shared__ __align__(16) float Cs[C * 132];    // dim-major [d][r], pad->132
  __shared__ float cn[128];
  const int t = threadIdx.x;
  const int qb = blockIdx.x * 64;
  const int tb = blockIdx.y ? 11 : 0;
  const int nt = blockIdx.y ? 10 : 11;           // 21 tiles total

  if constexpr (C == 64) {
#pragma unroll
    for (int u = 0; u < 4; ++u) {
      int idx = u * 256 + t;
      int q = idx & 63, dg = idx >> 6;
      f4 v = *(const f4*)&X[(size_t)(qb + q) * C + dg * 4];
#pragma unroll
      for (int e = 0; e < 4; ++e) Qs[(dg * 4 + e) * 64 + q] = v[e];
    }
  } else {
    for (int idx = t; idx < C * 64; idx += 256) {
      int q = idx & 63, d = idx >> 6;
      Qs[d * 64 + q] = X[(size_t)(qb + q) * C + d];
    }
  }

  const int tq = t & 15, tc = t >> 4;
  const int q0 = tq * 4, c0 = tc * 8;

  float l4[4][4]; float km[4];
#pragma unroll
  for (int i = 0; i < 4; ++i) {
    km[i] = FLT_MAX;
#pragma unroll
    for (int k = 0; k < 4; ++k) l4[i][k] = FLT_MAX;
  }

  for (int tt = 0; tt < nt; ++tt) {
    const int base = (tb + tt) * 128;
    __syncthreads();
    if constexpr (C == 64) {
#pragma unroll
      for (int u = 0; u < 8; ++u) {
        int idx = u * 256 + t;
        int r = idx & 127, dg = idx >> 7;
        f4 v = *(const f4*)&X[(size_t)((base + r) * 6) * C + dg * 4];
#pragma unroll
        for (int e = 0; e < 4; ++e) Cs[(dg * 4 + e) * 132 + r] = v[e];
      }
    } else {
      for (int idx = t; idx < C * 128; idx += 256) {
        int r = idx & 127, d = idx >> 7;
        Cs[d * 132 + r] = X[(size_t)((base + r) * 6) * C + d];
      }
    }
    if (t < 128) cn[t] = vn[(base + t) * 6];
    __syncthreads();

    float acc[4][8];
#pragma unroll
    for (int i = 0; i < 4; ++i)
#pragma unroll
      for (int j = 0; j < 8; ++j) acc[i][j] = 0.f;

#pragma unroll 4
    for (int d = 0; d < C; ++d) {
      f4 qa = *(const f4*)&Qs[d * 64 + q0];
      f4 ca = *(const f4*)&Cs[d * 132 + c0];
      f4 cb = *(const f4*)&Cs[d * 132 + c0 + 4];
      float cr[8] = {ca[0], ca[1], ca[2], ca[3], cb[0], cb[1], cb[2], cb[3]};
#pragma unroll
      for (int i = 0; i < 4; ++i)
#pragma unroll
        for (int j = 0; j < 8; ++j)
          acc[i][j] = fmaf(qa[i], cr[j], acc[i][j]);
    }

#pragma unroll
    for (int j = 0; j < 8; ++j) {
      float cv = cn[c0 + j];
#pragma unroll
      for (int i = 0; i < 4; ++i) {
        float sv = fmaf(-2.f, acc[i][j], cv);
        if (sv < km[i]) ins4(l4[i], km[i], sv);
      }
    }
  }

#pragma unroll
  for (int i = 0; i < 4; ++i) {
    size_t off = (((size_t)blockIdx.y * NPTS + (qb + q0 + i)) * 16 + tc) * 4;
    f4 v = {l4[i][0], l4[i][1], l4[i][2], l4[i][3]};
    *(f4*)&plist[off] = v;
  }
}

// ---------------- merge plist -> T; zero cnt/redoCnt ----------------
__global__ __launch_bounds__(256)
void mergeT_kernel(const float* __restrict__ plist, float* __restrict__ T,
                   unsigned* __restrict__ cnt, unsigned* __restrict__ redoCnt) {
  const int q = blockIdx.x * 256 + threadIdx.x;
  float td[KK];
#pragma unroll
  for (int j = 0; j < KK; ++j) td[j] = FLT_MAX;
  float km = FLT_MAX;
  for (int s = 0; s < 2; ++s) {
    const float* p = &plist[((size_t)s * NPTS + q) * 64];
    for (int z = 0; z < 64; ++z) {
      float v = p[z];
      if (v < km) ins20(td, km, v);
    }
  }
  T[q] = td[KK - 1] + 1e-4f * (fabsf(td[KK - 1]) + 1.0f);
  cnt[q] = 0u;
  if (q == 0) *redoCnt = 0u;
}

// ---------------- phase F (C=3): register-query filter + LDS survivor aggregation --
// CAPB=28 keeps LDS ~37 KB -> 4 blocks/CU. Overflow falls back to global append.
__global__ __launch_bounds__(256, 4)
void knn_filter3_kernel(const float* __restrict__ X, const float* __restrict__ vn,
                        const float* __restrict__ T,
                        float* __restrict__ survd, int* __restrict__ survi,
                        unsigned* __restrict__ cnt) {
  constexpr int CAPB = 28;
  __shared__ __align__(16) f4 CsV[512];            // (x,y,z,vn) packed, 8 KB
  __shared__ float Tsl[128];
  __shared__ unsigned scnt[128];
  __shared__ float sbD[128 * CAPB];
  __shared__ int   sbI[128 * CAPB];

  const int t = threadIdx.x;
  const int qb = blockIdx.x * 128;
  const int cbase = blockIdx.y * 2048;
  if (t < 128) { Tsl[t] = T[qb + t]; scnt[t] = 0u; }
  __syncthreads();

  const int tq = t & 15, tc = t >> 4;
  const int q0 = tq * 8, c0loc = tc * 8;

  float qx[8], qy[8], qz[8], tr[8];
#pragma unroll
  for (int i = 0; i < 8; ++i) {
    const float* qr = &X[(size_t)(qb + q0 + i) * 3];
    qx[i] = qr[0]; qy[i] = qr[1]; qz[i] = qr[2];
    tr[i] = Tsl[q0 + i];
  }

  for (int rd = 0; rd < 4; ++rd) {
    const int cb = cbase + rd * 512;
    __syncthreads();   // prior round's CsV reads done
#pragma unroll
    for (int u = 0; u < 2; ++u) {
      int idx = u * 256 + t;
      int c = cb + idx;
      const float* cr = &X[(size_t)c * 3];
      f4 v = {cr[0], cr[1], cr[2], vn[c]};
      CsV[idx] = v;
    }
    __syncthreads();

#pragma unroll
    for (int sub = 0; sub < 4; ++sub) {
      const int cl0 = sub * 128 + c0loc;
#pragma unroll
      for (int j = 0; j < 8; ++j) {
        f4 cv = CsV[cl0 + j];
        const int cglob = cb + cl0 + j;
#pragma unroll
        for (int i = 0; i < 8; ++i) {
          float d0 = fmaf(qx[i], cv[0], fmaf(qy[i], cv[1], qz[i] * cv[2]));
          float sv = fmaf(-2.f, d0, cv[3]);
          if (sv <= tr[i]) {
            unsigned p = atomicAdd(&scnt[q0 + i], 1u);
            if (p < CAPB) {
              sbD[(q0 + i) * CAPB + p] = sv;
              sbI[(q0 + i) * CAPB + p] = cglob;
            } else {  // rare fallback: direct global append
              unsigned gp = atomicAdd(&cnt[qb + q0 + i], 1u);
              if (gp < SURV_CAP) {
                survd[(size_t)(qb + q0 + i) * SURV_CAP + gp] = sv;
                survi[(size_t)(qb + q0 + i) * SURV_CAP + gp] = cglob;
              }
            }
          }
        }
      }
    }
  }

  __syncthreads();
  if (t < 128) {
    unsigned n = scnt[t]; if (n > CAPB) n = CAPB;
    if (n) {
      unsigned base = atomicAdd(&cnt[qb + t], n);
      for (unsigned i = 0; i < n; ++i) {
        unsigned p = base + i;
        if (p < SURV_CAP) {
          survd[(size_t)(qb + t) * SURV_CAP + p] = sbD[t * CAPB + i];
          survi[(size_t)(qb + t) * SURV_CAP + p] = sbI[t * CAPB + i];
        }
      }
    }
  }
}

// ---------------- phase F (C=64): MFMA bf16 filter + LDS survivor aggregation ------
__global__ __launch_bounds__(256, 2)
void knn_filter64_mfma(const short* __restrict__ Xbf, const float* __restrict__ vn,
                       const float* __restrict__ sn, const float* __restrict__ T,
                       int* __restrict__ survi, unsigned* __restrict__ cnt) {
  __shared__ __align__(16) short Qs[128 * 64];
  __shared__ __align__(16) short Cs[128 * 64];
  __shared__ float vnc[128], snq[128], snc[128], Tq[128];
  __shared__ unsigned scnt[128];
  __shared__ int sbI[128 * 8];

  const int t = threadIdx.x;
  const int qb = blockIdx.x * 128, cb = blockIdx.y * 128;

#pragma unroll
  for (int p = 0; p < 4; ++p) {
    int idx = p * 256 + t;
    int row = idx >> 3, sl = idx & 7;
    int slq = sl ^ (row & 7);
    *(bh8*)&Qs[row * 64 + slq * 8] = *(const bh8*)&Xbf[(size_t)(qb + row) * 64 + sl * 8];
    *(bh8*)&Cs[row * 64 + slq * 8] = *(const bh8*)&Xbf[(size_t)(cb + row) * 64 + sl * 8];
  }
  if (t < 128) { Tq[t] = T[qb + t]; snq[t] = sn[qb + t]; scnt[t] = 0u; }
  else { vnc[t - 128] = vn[cb + t - 128]; snc[t - 128] = sn[cb + t - 128]; }
  __syncthreads();

  const int w = t >> 6, l = t & 63;
  const int qsub = (w >> 1) * 64, csub = (w & 1) * 64;
  const int lr = l & 15, lh = l >> 4;

  f32x4 acc[4][4];
#pragma unroll
  for (int i = 0; i < 4; ++i)
#pragma unroll
    for (int j = 0; j < 4; ++j) acc[i][j] = f32x4{0.f, 0.f, 0.f, 0.f};

#pragma unroll
  for (int kk = 0; kk < 2; ++kk) {
    const int sl = kk * 4 + lh;
    bh8 af[4], bf[4];
#pragma unroll
    for (int i = 0; i < 4; ++i) {
      int qr = qsub + i * 16 + lr;
      af[i] = *(const bh8*)&Qs[qr * 64 + (sl ^ (qr & 7)) * 8];
      int cr = csub + i * 16 + lr;
      bf[i] = *(const bh8*)&Cs[cr * 64 + (sl ^ (cr & 7)) * 8];
    }
#pragma unroll
    for (int i = 0; i < 4; ++i)
#pragma unroll
      for (int j = 0; j < 4; ++j)
        acc[i][j] = __builtin_amdgcn_mfma_f32_16x16x32_bf16(af[i], bf[j], acc[i][j], 0, 0, 0);
  }

#pragma unroll
  for (int i = 0; i < 4; ++i) {
#pragma unroll
    for (int r = 0; r < 4; ++r) {
      const int ql = qsub + i * 16 + lh * 4 + r;
      const float tcut = Tq[ql];
      const float sq = snq[ql];
      const int q = qb + ql;
#pragma unroll
      for (int j = 0; j < 4; ++j) {
        const int cl = csub + j * 16 + lr;
        float s = fmaf(-2.f, acc[i][j][r], vnc[cl]);
        float margin = 0.0082f * sq * snc[cl] + 1e-6f;
        if (s <= tcut + margin) {
          unsigned p = atomicAdd(&scnt[ql], 1u);
          if (p < 8u) sbI[ql * 8 + p] = cb + cl;
          else {  // rare fallback
            unsigned gp = atomicAdd(&cnt[q], 1u);
            if (gp < SURV_CAP) survi[(size_t)q * SURV_CAP + gp] = cb + cl;
          }
        }
      }
    }
  }

  __syncthreads();
  if (t < 128) {
    unsigned n = scnt[t]; if (n > 8u) n = 8u;
    if (n) {
      unsigned base = atomicAdd(&cnt[qb + t], n);
      for (unsigned i = 0; i < n; ++i) {
        unsigned p = base + i;
        if (p < SURV_CAP) survi[(size_t)(qb + t) * SURV_CAP + p] = sbI[t * 8 + i];
      }
    }
  }
}

// ---------------- exact fp32 recompute of survivor distances (C=64 path) ----------
template<int C>
__global__ __launch_bounds__(256, 2)
void exact_kernel(const float* __restrict__ X, int ldx, const float* __restrict__ vn,
                  const unsigned* __restrict__ cnt, const int* __restrict__ survi,
                  float* __restrict__ survd) {
  __shared__ float qsh[C];
  const int q = blockIdx.x;
  const int t = threadIdx.x;
  if (t < C) qsh[t] = X[(size_t)q * ldx + t];
  __syncthreads();
  unsigned n = cnt[q];
  if (n > SURV_CAP) n = SURV_CAP;
  if (t < n) {
    const int c = survi[(size_t)q * SURV_CAP + t];
    const float* crow = X + (size_t)c * ldx;
    float d0 = 0.f, d1 = 0.f, d2 = 0.f, d3 = 0.f;
#pragma unroll
    for (int s = 0; s < C / 4; ++s) {
      f4 cv = *(const f4*)&crow[s * 4];
      d0 = fmaf(cv[0], qsh[s * 4 + 0], d0);
      d1 = fmaf(cv[1], qsh[s * 4 + 1], d1);
      d2 = fmaf(cv[2], qsh[s * 4 + 2], d2);
      d3 = fmaf(cv[3], qsh[s * 4 + 3], d3);
    }
    survd[(size_t)q * SURV_CAP + t] = fmaf(-2.f, (d0 + d1) + (d2 + d3), vn[c]);
  }
}

// ---------------- phase Sel: exact top-20 among survivors (overflow -> redo list) --
// grid 256 x 64 threads: one thread per query, spread across all CUs.
__global__ __launch_bounds__(64, 8)
void select_kernel(const float* __restrict__ survd, const int* __restrict__ survi,
                   const unsigned* __restrict__ cnt, int* __restrict__ ind,
                   unsigned* __restrict__ redoCnt, int* __restrict__ redoList) {
  const int q = blockIdx.x * 64 + threadIdx.x;
  const unsigned n = cnt[q];
  if (n > SURV_CAP) {   // dense-cluster overflow: defer to parallel redo kernels
    unsigned p = atomicAdd(redoCnt, 1u);
    redoList[p] = q;
    return;
  }
  float td[KK]; int ti[KK];
#pragma unroll
  for (int j = 0; j < KK; ++j) { td[j] = FLT_MAX; ti[j] = 0; }
  float kmax = FLT_MAX;
  for (unsigned i = 0; i < n; ++i) {
    float d = survd[(size_t)q * SURV_CAP + i];
    if (d < kmax) ins20p(td, ti, kmax, d, survi[(size_t)q * SURV_CAP + i]);
  }
#pragma unroll
  for (int j = 0; j < KK; ++j) ind[q * KK + j] = ti[j];
}

// ---------------- redo pass 1: 32 blocks per query, each scans a 512-cand slab ----
template<int C>
__global__ __launch_bounds__(256, 2)
void knn_redo_p1(const float* __restrict__ X, int ldx, const float* __restrict__ vn,
                 const int* __restrict__ redoList, const unsigned* __restrict__ redoCnt,
                 float* __restrict__ rpd, int* __restrict__ rpi) {
  __shared__ float lds_d[256 * KK];
  __shared__ int   lds_i[256 * KK];
  const int t = threadIdx.x;
  const unsigned n = *redoCnt;
  const unsigned e = blockIdx.x >> 5;
  const int part = blockIdx.x & 31;
  if (e >= n || e >= (unsigned)RQSLOTS) return;
  const int q = redoList[e];
  float qreg[C];
#pragma unroll
  for (int d = 0; d < C; ++d) qreg[d] = X[(size_t)q * ldx + d];
  float td[KK]; int ti[KK];
#pragma unroll
  for (int j = 0; j < KK; ++j) { td[j] = FLT_MAX; ti[j] = 0; }
  float kmax = FLT_MAX;
  const int cbase = part * 512;
#pragma unroll
  for (int u = 0; u < 2; ++u) {
    const int c = cbase + u * 256 + t;
    const float* crow = X + (size_t)c * ldx;
    float d0 = 0.f;
    if constexpr (C >= 4) {
      float d1 = 0.f, d2 = 0.f, d3 = 0.f;
#pragma unroll
      for (int s = 0; s < C / 4; ++s) {
        f4 cv = *(const f4*)&crow[s * 4];
        d0 = fmaf(cv[0], qreg[s * 4 + 0], d0);
        d1 = fmaf(cv[1], qreg[s * 4 + 1], d1);
        d2 = fmaf(cv[2], qreg[s * 4 + 2], d2);
        d3 = fmaf(cv[3], qreg[s * 4 + 3], d3);
      }
      d0 = (d0 + d1) + (d2 + d3);
    } else {
#pragma unroll
      for (int d = 0; d < C; ++d) d0 = fmaf(crow[d], qreg[d], d0);
    }
    float sv = fmaf(-2.f, d0, vn[c]);
    if (sv < kmax) ins20p(td, ti, kmax, sv, c);
  }
#pragma unroll
  for (int j = 0; j < KK; ++j) { lds_d[t * KK + j] = td[j]; lds_i[t * KK + j] = ti[j]; }
  __syncthreads();
  // tree merge 256 -> 64 -> 16 -> 4 -> 1 (early-break keeps sparse lists cheap)
#pragma unroll
  for (int G = 1; G <= 64; G *= 4) {
    const int nth = (G == 64) ? 1 : (G == 16) ? 4 : (G == 4) ? 16 : 64;
    if (t < nth) {
      float md[KK]; int mi[KK];
#pragma unroll
      for (int j = 0; j < KK; ++j) { md[j] = FLT_MAX; mi[j] = 0; }
      float km = FLT_MAX;
      for (int s = 0; s < 4; ++s) {
        int base = ((t * 4 + s) * G) * KK;
        for (int j = 0; j < KK; ++j) {
          float v = lds_d[base + j];
          if (v < km) ins20p(md, mi, km, v, lds_i[base + j]);
          else break;
        }
      }
      int obase = (t * 4 * G) * KK;
#pragma unroll
      for (int j = 0; j < KK; ++j) { lds_d[obase + j] = md[j]; lds_i[obase + j] = mi[j]; }
    }
    __syncthreads();
  }
  if (t == 0) {
    size_t off = ((size_t)e * 32 + part) * KK;
#pragma unroll
    for (int j = 0; j < KK; ++j) { rpd[off + j] = lds_d[j]; rpi[off + j] = lds_i[j]; }
  }
}

// ---------------- redo pass 2: one thread per query merges its 32 sorted lists ----
__global__ __launch_bounds__(256)
void knn_redo_p2(const int* __restrict__ redoList, const unsigned* __restrict__ redoCnt,
                 const float* __restrict__ rpd, const int* __restrict__ rpi,
                 int* __restrict__ ind) {
  const unsigned e = blockIdx.x * 256 + threadIdx.x;
  const unsigned n = *redoCnt;
  if (e >= n || e >= (unsigned)RQSLOTS) return;
  const int q = redoList[e];
  float td[KK]; int ti[KK];
#pragma unroll
  for (int j = 0; j < KK; ++j) { td[j] = FLT_MAX; ti[j] = 0; }
  float kmax = FLT_MAX;
  for (int p = 0; p < 32; ++p) {
    const float* dd = &rpd[((size_t)e * 32 + p) * KK];
    const int* ii = &rpi[((size_t)e * 32 + p) * KK];
    for (int j = 0; j < KK; ++j) {
      float v = dd[j];
      if (v < kmax) ins20p(td, ti, kmax, v, ii[j]);
      else break;   // lists sorted ascending
    }
  }
#pragma unroll
  for (int j = 0; j < KK; ++j) ind[q * KK + j] = ti[j];
}

// ---------------- redo fallback: whole-scan per block for e >= RQSLOTS (rare) ------
template<int C>
__global__ __launch_bounds__(256, 2)
void knn_redo_kernel(const float* __restrict__ X, int ldx, const float* __restrict__ vn,
                     const int* __restrict__ redoList, const unsigned* __restrict__ redoCnt,
                     int* __restrict__ ind, unsigned ebase) {
  __shared__ float lds_d[256 * KK];
  __shared__ int   lds_i[256 * KK];
  const int t = threadIdx.x;
  const unsigned n = *redoCnt;
  for (unsigned e = ebase + blockIdx.x; e < n; e += gridDim.x) {
    const int q = redoList[e];
    float qreg[C];
#pragma unroll
    for (int d = 0; d < C; ++d) qreg[d] = X[(size_t)q * ldx + d];
    float td[KK]; int ti[KK];
#pragma unroll
    for (int j = 0; j < KK; ++j) { td[j] = FLT_MAX; ti[j] = 0; }
    float kmax = FLT_MAX;
    for (int c = t; c < NPTS; c += 256) {
      const float* crow = X + (size_t)c * ldx;
      float d0 = 0.f;
      if constexpr (C >= 4) {
        float d1 = 0.f, d2 = 0.f, d3 = 0.f;
#pragma unroll
        for (int s = 0; s < C / 4; ++s) {
          f4 cv = *(const f4*)&crow[s * 4];
          d0 = fmaf(cv[0], qreg[s * 4 + 0], d0);
          d1 = fmaf(cv[1], qreg[s * 4 + 1], d1);
          d2 = fmaf(cv[2], qreg[s * 4 + 2], d2);
          d3 = fmaf(cv[3], qreg[s * 4 + 3], d3);
        }
        d0 = (d0 + d1) + (d2 + d3);
      } else {
#pragma unroll
        for (int d = 0; d < C; ++d) d0 = fmaf(crow[d], qreg[d], d0);
      }
      float sv = fmaf(-2.f, d0, vn[c]);
      if (sv < kmax) ins20p(td, ti, kmax, sv, c);
    }
#pragma unroll
    for (int j = 0; j < KK; ++j) { lds_d[t * KK + j] = td[j]; lds_i[t * KK + j] = ti[j]; }
    __syncthreads();
#pragma unroll
    for (int G = 1; G <= 64; G *= 4) {
      const int nth = (G == 64) ? 1 : (G == 16) ? 4 : (G == 4) ? 16 : 64;
      if (t < nth) {
        float md[KK]; int mi[KK];
#pragma unroll
        for (int j = 0; j < KK; ++j) { md[j] = FLT_MAX; mi[j] = 0; }
        float km = FLT_MAX;
        for (int s = 0; s < 4; ++s) {
          int base = ((t * 4 + s) * G) * KK;
          for (int j = 0; j < KK; ++j) {
            float v = lds_d[base + j];
            if (v < km) ins20p(md, mi, km, v, lds_i[base + j]);
            else break;
          }
        }
        int obase = (t * 4 * G) * KK;
#pragma unroll
        for (int j = 0; j < KK; ++j) { lds_d[obase + j] = md[j]; lds_i[obase + j] = mi[j]; }
      }
      __syncthreads();
    }
    if (t == 0) {
#pragma unroll
      for (int j = 0; j < KK; ++j) ind[q * KK + j] = lds_i[j];
    }
    __syncthreads();
  }
}

// ---------------- UB precompute: U = x@W1_top, B = x@(W1_bot - W1_top) ------------
template<int CIN>
__global__ __launch_bounds__(256, 2)
void ub_kernel(const float* __restrict__ X, int ldx, const float* __restrict__ W1,
               float* __restrict__ UB) {
  __shared__ __align__(16) float Ws[2 * CIN * 64];
  __shared__ __align__(16) float Xs[32][(CIN == 3) ? 4 : CIN];
  const int t = threadIdx.x;
  for (int idx = t; idx < 2 * CIN * 64; idx += 256) Ws[idx] = W1[idx];
  const int pb = blockIdx.x * 32;
  if constexpr (CIN == 64) {
    int r = t >> 3, g = t & 7;
    f4 a = *(const f4*)&X[(size_t)(pb + r) * ldx + g * 8];
    f4 b = *(const f4*)&X[(size_t)(pb + r) * ldx + g * 8 + 4];
    *(f4*)&Xs[r][g * 8] = a;
    *(f4*)&Xs[r][g * 8 + 4] = b;
  } else {
    if (t < 32 * CIN) {
      int r = t / CIN, d = t - r * CIN;
      Xs[r][d] = X[(size_t)(pb + r) * ldx + d];
    }
  }
  __syncthreads();
  const int p = t >> 3, c0 = (t & 7) * 8;
  float u[8], v[8];
#pragma unroll
  for (int e = 0; e < 8; ++e) { u[e] = 0.f; v[e] = 0.f; }
#pragma unroll 4
  for (int k = 0; k < CIN; ++k) {
    float xv = Xs[p][k];
    f4 wt0 = *(const f4*)&Ws[k * 64 + c0];
    f4 wt1 = *(const f4*)&Ws[k * 64 + c0 + 4];
    f4 wb0 = *(const f4*)&Ws[(CIN + k) * 64 + c0];
    f4 wb1 = *(const f4*)&Ws[(CIN + k) * 64 + c0 + 4];
#pragma unroll
    for (int e = 0; e < 4; ++e) {
      u[e]     = fmaf(xv, wt0[e], u[e]);
      u[4 + e] = fmaf(xv, wt1[e], u[4 + e]);
      v[e]     = fmaf(xv, wb0[e], v[e]);
      v[4 + e] = fmaf(xv, wb1[e], v[4 + e]);
    }
  }
  float* o = &UB[(size_t)(pb + p) * 128];
  f4 a0 = {u[0], u[1], u[2], u[3]}, a1 = {u[4], u[5], u[6], u[7]};
  f4 b0 = {v[0] - u[0], v[1] - u[1], v[2] - u[2], v[3] - u[3]};
  f4 b1 = {v[4] - u[4], v[5] - u[5], v[6] - u[6], v[7] - u[7]};
  *(f4*)&o[c0] = a0;       *(f4*)&o[c0 + 4] = a1;
  *(f4*)&o[64 + c0] = b0;  *(f4*)&o[64 + c0 + 4] = b1;
}

// ---------------- edgeconv TWO-layer: h1 = prelu(U[nb]+B[i]); out = max prelu(h1@W2)
__global__ __launch_bounds__(256, 3)
void edgeconv2_kernel(const float* __restrict__ UB, const int* __restrict__ ind,
                      const float* __restrict__ W2, const float* __restrict__ p1p,
                      const float* __restrict__ p2p,
                      float* __restrict__ Y, int ldy) {
  __shared__ __align__(16) float W2s[64 * 64];     // 16 KB
  __shared__ __align__(16) float h1[4][64 * 32];   // 32 KB, [c][kslot]
  __shared__ float Bs[4][64];
  __shared__ int nbs[4][KK];
  const int t = threadIdx.x;
  const int w = t >> 6, l = t & 63;
  const float a1 = *p1p, a2 = *p2p;
  const int i = blockIdx.x * 4 + w;
  for (int idx = t; idx < 64 * 64; idx += 256) W2s[idx] = W2[idx];
  if (l < 16) *(f4*)&Bs[w][l * 4] = *(const f4*)&UB[(size_t)i * 128 + 64 + l * 4];
  if (l < KK) nbs[w][l] = ind[i * KK + l];
  __syncthreads();

  {  // build h1 for this warp's point: lane -> (kslot, channel half)
    const int kslot = l >> 1, ch0 = (l & 1) * 32;
    if (kslot < KK) {
      const int nb = nbs[w][kslot];
      const float* ur = &UB[(size_t)nb * 128 + ch0];
#pragma unroll
      for (int g = 0; g < 8; ++g) {
        f4 uv = *(const f4*)&ur[g * 4];
#pragma unroll
        for (int e = 0; e < 4; ++e) {
          int c = ch0 + g * 4 + e;
          float hv = uv[e] + Bs[w][c];
          hv = fmaxf(hv, 0.f) + a1 * fminf(hv, 0.f);
          h1[w][c * 32 + kslot] = hv;
        }
      }
    } else {
#pragma unroll
      for (int g = 0; g < 32; ++g) h1[w][(ch0 + g) * 32 + kslot] = 0.f;
    }
  }
  __syncthreads();

  // GEMM2: lane = kg*8+cg, tile 4nb x 8ch over padded 32 neighbors
  const int kg = l >> 3, cg = l & 7;
  const int k0 = kg * 4, c0 = cg * 8;
  float acc[4][8];
#pragma unroll
  for (int a = 0; a < 4; ++a)
#pragma unroll
    for (int b = 0; b < 8; ++b) acc[a][b] = 0.f;
#pragma unroll 4
  for (int c = 0; c < 64; ++c) {
    f4 hv = *(const f4*)&h1[w][c * 32 + k0];
    f4 w0 = *(const f4*)&W2s[c * 64 + c0];
    f4 w1 = *(const f4*)&W2s[c * 64 + c0 + 4];
    float wr[8] = {w0[0], w0[1], w0[2], w0[3], w1[0], w1[1], w1[2], w1[3]};
#pragma unroll
    for (int a = 0; a < 4; ++a)
#pragma unroll
      for (int b = 0; b < 8; ++b)
        acc[a][b] = fmaf(hv[a], wr[b], acc[a][b]);
  }

  // prelu + masked max (20 = 5 full groups of 4; kg>=5 are pad)
  float mx[8];
#pragma unroll
  for (int b = 0; b < 8; ++b) mx[b] = -FLT_MAX;
  if (kg < 5) {
#pragma unroll
    for (int a = 0; a < 4; ++a)
#pragma unroll
      for (int b = 0; b < 8; ++b) {
        float v = fmaxf(acc[a][b], 0.f) + a2 * fminf(acc[a][b], 0.f);
        mx[b] = fmaxf(mx[b], v);
      }
  }
#pragma unroll
  for (int b = 0; b < 8; ++b) {
    mx[b] = fmaxf(mx[b], __shfl_xor(mx[b], 8));
    mx[b] = fmaxf(mx[b], __shfl_xor(mx[b], 16));
    mx[b] = fmaxf(mx[b], __shfl_xor(mx[b], 32));
  }
  if (kg == 0) {
    f4 o0 = {mx[0], mx[1], mx[2], mx[3]}, o1 = {mx[4], mx[5], mx[6], mx[7]};
    float* yp = &Y[(size_t)i * ldy + c0];
    *(f4*)yp = o0;
    *(f4*)(yp + 4) = o1;
  }
}

// ---------------- edgeconv ONE-layer: out[i][c] = max_k prelu(U[nb][c]+B[i][c]) ----
__global__ __launch_bounds__(256, 4)
void edgeconv1_kernel(const float* __restrict__ UB, const int* __restrict__ ind,
                      const float* __restrict__ p1p, float* __restrict__ Y, int ldy) {
  __shared__ int nbs[4][KK];
  __shared__ float Bs[4][64];
  const int t = threadIdx.x;
  const int w = t >> 6, l = t & 63;
  const float a1 = *p1p;
  const int i = blockIdx.x * 4 + w;
  if (l < KK) nbs[w][l] = ind[i * KK + l];
  if (l < 16) *(f4*)&Bs[w][l * 4] = *(const f4*)&UB[(size_t)i * 128 + 64 + l * 4];
  __syncthreads();
  const float b = Bs[w][l];
  float mx = -FLT_MAX;
#pragma unroll 4
  for (int k = 0; k < KK; ++k) {
    float uv = UB[(size_t)nbs[w][k] * 128 + l];
    float hv = uv + b;
    hv = fmaxf(hv, 0.f) + a1 * fminf(hv, 0.f);
    mx = fmaxf(mx, hv);
  }
  Y[(size_t)i * ldy + l] = mx;
}

// ---------------- ordered-float encode for atomicMax ----------------
__device__ __forceinline__ unsigned fenc(float f) {
  unsigned u = __float_as_uint(f);
  return (u & 0x80000000u) ? ~u : (u | 0x80000000u);
}
__device__ __forceinline__ float fdec(unsigned u) {
  return (u & 0x80000000u) ? __uint_as_float(u & 0x7fffffffu) : __uint_as_float(~u);
}

__global__ void initg_kernel(unsigned* __restrict__ g) {
  g[blockIdx.x * 256 + threadIdx.x] = 0x007FFFFFu;  // fenc(-inf)
}

// ---------------- split fp32 -> (hi, lo) bf16, flat over n8 groups of 8 ----------
__global__ __launch_bounds__(256)
void splitA_kernel(const float* __restrict__ X, int n8,
                   short* __restrict__ hi, short* __restrict__ lo) {
  int idx = blockIdx.x * 256 + threadIdx.x;
  if (idx >= n8) return;
  f4 a = *(const f4*)&X[(size_t)idx * 8];
  f4 b = *(const f4*)&X[(size_t)idx * 8 + 4];
  bh8 h, w;
#pragma unroll
  for (int e = 0; e < 4; ++e) {
    float v0 = a[e], v1 = b[e];
    __hip_bfloat16 h0 = __float2bfloat16(v0);
    __hip_bfloat16 h1 = __float2bfloat16(v1);
    __hip_bfloat16 l0 = __float2bfloat16(v0 - __bfloat162float(h0));
    __hip_bfloat16 l1 = __float2bfloat16(v1 - __bfloat162float(h1));
    h[e] = *reinterpret_cast<short*>(&h0); h[4 + e] = *reinterpret_cast<short*>(&h1);
    w[e] = *reinterpret_cast<short*>(&l0); w[4 + e] = *reinterpret_cast<short*>(&l1);
  }
  *(bh8*)&hi[(size_t)idx * 8] = h;
  *(bh8*)&lo[(size_t)idx * 8] = w;
}

// ---------------- split + transpose W [K,ldw] -> Wt hi/lo [M][K] bf16 -------------
__global__ __launch_bounds__(256)
void splitWt_kernel(const float* __restrict__ W, int ldw, int M, int K,
                    short* __restrict__ hi, short* __restrict__ lo) {
  int idx = blockIdx.x * 256 + threadIdx.x;   // (c, kgroup8)
  int kg8 = K / 8;
  if (idx >= M * kg8) return;
  int c = idx / kg8, kg = idx - c * kg8;
  bh8 h, w;
#pragma unroll
  for (int e = 0; e < 8; ++e) {
    float v = W[(size_t)(kg * 8 + e) * ldw + c];
    __hip_bfloat16 hv = __float2bfloat16(v);
    __hip_bfloat16 lv = __float2bfloat16(v - __bfloat162float(hv));
    h[e] = *reinterpret_cast<short*>(&hv);
    w[e] = *reinterpret_cast<short*>(&lv);
  }
  *(bh8*)&hi[(size_t)c * K + kg * 8] = h;
  *(bh8*)&lo[(size_t)c * K + kg * 8] = w;
}

// ---------------- split-bf16 MFMA GEMM + prelu; MODE 1: colmax, MODE 2: bias+store -
template<int MODE, int K>
__global__ __launch_bounds__(256, 2)
void gemm_mfma_kernel(const short* __restrict__ Ahi, const short* __restrict__ Alo,
                      const short* __restrict__ Wthi, const short* __restrict__ Wtlo,
                      const float* __restrict__ bias, const float* __restrict__ pptr,
                      float* __restrict__ Cm, int ldc, unsigned* __restrict__ gmax) {
  __shared__ __align__(16) short Ah[128 * 32], Al[128 * 32];
  __shared__ __align__(16) short Bh[128 * 32], Bl[128 * 32];   // 32 KB total
  const int t = threadIdx.x;
  const int rb = blockIdx.x * 128, cb = blockIdx.y * 128;
  const float aa = *pptr;
  const int w = t >> 6, l = t & 63;
  const int rsub = (w >> 1) * 64, csub = (w & 1) * 64;
  const int lr = l & 15, lh = l >> 4;

  f32x4 acc[4][4];
#pragma unroll
  for (int i = 0; i < 4; ++i)
#pragma unroll
    for (int j = 0; j < 4; ++j) acc[i][j] = f32x4{0.f, 0.f, 0.f, 0.f};

  for (int ck = 0; ck < K; ck += 32) {
    __syncthreads();
#pragma unroll
    for (int u = 0; u < 2; ++u) {
      int idx = u * 256 + t;          // 0..511 = 128 rows x 4 slots
      int row = idx >> 2, s = idx & 3;
      int ssw = s ^ (row & 3);
      *(bh8*)&Ah[row * 32 + ssw * 8] = *(const bh8*)&Ahi[(size_t)(rb + row) * K + ck + s * 8];
      *(bh8*)&Al[row * 32 + ssw * 8] = *(const bh8*)&Alo[(size_t)(rb + row) * K + ck + s * 8];
      *(bh8*)&Bh[row * 32 + ssw * 8] = *(const bh8*)&Wthi[(size_t)(cb + row) * K + ck + s * 8];
      *(bh8*)&Bl[row * 32 + ssw * 8] = *(const bh8*)&Wtlo[(size_t)(cb + row) * K + ck + s * 8];
    }
    __syncthreads();
    bh8 ah[4], al[4], bh_[4], bl_[4];
#pragma unroll
    for (int i = 0; i < 4; ++i) {
      int r = rsub + i * 16 + lr;
      int ssw = lh ^ (r & 3);
      ah[i] = *(const bh8*)&Ah[r * 32 + ssw * 8];
      al[i] = *(const bh8*)&Al[r * 32 + ssw * 8];
      int c = csub + i * 16 + lr;
      int csw = lh ^ (c & 3);
      bh_[i] = *(const bh8*)&Bh[c * 32 + csw * 8];
      bl_[i] = *(const bh8*)&Bl[c * 32 + csw * 8];
    }
#pragma unroll
    for (int i = 0; i < 4; ++i)
#pragma unroll
      for (int j = 0; j < 4; ++j) {
        acc[i][j] = __builtin_amdgcn_mfma_f32_16x16x32_bf16(ah[i], bh_[j], acc[i][j], 0, 0, 0);
        acc[i][j] = __builtin_amdgcn_mfma_f32_16x16x32_bf16(ah[i], bl_[j], acc[i][j], 0, 0, 0);
        acc[i][j] = __builtin_amdgcn_mfma_f32_16x16x32_bf16(al[i], bh_[j], acc[i][j], 0, 0, 0);
      }
  }

  if (MODE == 1) {   // prelu + column max -> gmax (fenc atomic)
    float cmax[4];
#pragma unroll
    for (int j = 0; j < 4; ++j) cmax[j] = -FLT_MAX;
#pragma unroll
    for (int i = 0; i < 4; ++i)
#pragma unroll
      for (int r = 0; r < 4; ++r)
#pragma unroll
        for (int j = 0; j < 4; ++j) {
          float v = acc[i][j][r];
          v = fmaxf(v, 0.f) + aa * fminf(v, 0.f);
          cmax[j] = fmaxf(cmax[j], v);
        }
#pragma unroll
    for (int j = 0; j < 4; ++j) {
      cmax[j] = fmaxf(cmax[j], __shfl_xor(cmax[j], 16));
      cmax[j] = fmaxf(cmax[j], __shfl_xor(cmax[j], 32));
    }
    if (l < 16) {
#pragma unroll
      for (int j = 0; j < 4; ++j)
        atomicMax(&gmax[cb + csub + j * 16 + l], fenc(cmax[j]));
    }
  } else {           // bias + prelu + store
#pragma unroll
    for (int i = 0; i < 4; ++i)
#pragma unroll
      for (int r = 0; r < 4; ++r) {
        const int row = rsub + i * 16 + lh * 4 + r;
#pragma unroll
        for (int j = 0; j < 4; ++j) {
          const int col = csub + j * 16 + lr;
          float v = acc[i][j][r] + bias[cb + col];
          v = fmaxf(v, 0.f) + aa * fminf(v, 0.f);
          Cm[(size_t)(rb + row) * ldc + cb + col] = v;
        }
      }
  }
}

// ---------------- generic fp32 GEMM + prelu; MODE: 0 store, 1 colmax, 2 bias+store ----
template<int MODE>
__global__ __launch_bounds__(256, 2)
void gemm_kernel(const float* __restrict__ A, int lda,
                 const float* __restrict__ W, int ldw,
                 const float* __restrict__ bias,
                 const float* __restrict__ pptr,
                 float* __restrict__ Cm, int ldc, int Ktot,
                 unsigned* __restrict__ gmax) {
  __shared__ __align__(16) float At[16 * 132];
  __shared__ __align__(16) float Ws[16 * 128];
  const int t = threadIdx.x;
  const int rb = blockIdx.x * 128, cbb = blockIdx.y * 128;
  const int r0 = (t & 15) * 8, c0 = (t >> 4) * 8;
  const float aa = *pptr;

  float acc[8][8];
#pragma unroll
  for (int i = 0; i < 8; ++i)
#pragma unroll
    for (int j = 0; j < 8; ++j) acc[i][j] = 0.f;

  const int sr = t >> 1, skh = (t & 1) * 8;
  const int wk = t >> 4, wc = (t & 15) * 8;

  for (int k0 = 0; k0 < Ktot; k0 += 16) {
    __syncthreads();
    {
      const float* ap = &A[(size_t)(rb + sr) * lda + k0 + skh];
      f4 v0 = *(const f4*)ap;
      f4 v1 = *(const f4*)(ap + 4);
#pragma unroll
      for (int e = 0; e < 4; ++e) {
        At[(skh + e) * 132 + sr] = v0[e];
        At[(skh + 4 + e) * 132 + sr] = v1[e];
      }
      const float* wp = &W[(size_t)(k0 + wk) * ldw + cbb + wc];
      *(f4*)&Ws[wk * 128 + wc] = *(const f4*)wp;
      *(f4*)&Ws[wk * 128 + wc + 4] = *(const f4*)(wp + 4);
    }
    __syncthreads();
#pragma unroll 4
    for (int d = 0; d < 16; ++d) {
      f4 qa = *(const f4*)&At[d * 132 + r0];
      f4 qb = *(const f4*)&At[d * 132 + r0 + 4];
      f4 wa = *(const f4*)&Ws[d * 128 + c0];
      f4 wb = *(const f4*)&Ws[d * 128 + c0 + 4];
      float qr[8] = {qa[0], qa[1], qa[2], qa[3], qb[0], qb[1], qb[2], qb[3]};
      float wr[8] = {wa[0], wa[1], wa[2], wa[3], wb[0], wb[1], wb[2], wb[3]};
#pragma unroll
      for (int i = 0; i < 8; ++i)
#pragma unroll
        for (int j = 0; j < 8; ++j)
          acc[i][j] = fmaf(qr[i], wr[j], acc[i][j]);
    }
  }

  float bv[8];
#pragma unroll
  for (int j = 0; j < 8; ++j) bv[j] = (MODE == 2) ? bias[cbb + c0 + j] : 0.f;
#pragma unroll
  for (int i = 0; i < 8; ++i)
#pragma unroll
    for (int j = 0; j < 8; ++j) {
      float v = acc[i][j] + bv[j];
      acc[i][j] = fmaxf(v, 0.f) + aa * fminf(v, 0.f);
    }

  if (MODE == 1) {
    float cmax[8];
#pragma unroll
    for (int j = 0; j < 8; ++j) {
      cmax[j] = acc[0][j];
#pragma unroll
      for (int i = 1; i < 8; ++i) cmax[j] = fmaxf(cmax[j], acc[i][j]);
    }
    __syncthreads();
#pragma unroll
    for (int j = 0; j < 8; ++j) At[(t & 15) * 132 + c0 + j] = cmax[j];
    __syncthreads();
    if (t < 128) {
      float m = At[t];
      for (int rr = 1; rr < 16; ++rr) m = fmaxf(m, At[rr * 132 + t]);
      atomicMax(&gmax[cbb + t], fenc(m));
    }
  } else {
#pragma unroll
    for (int i = 0; i < 8; ++i) {
      f4 s0 = {acc[i][0], acc[i][1], acc[i][2], acc[i][3]};
      f4 s1 = {acc[i][4], acc[i][5], acc[i][6], acc[i][7]};
      float* cp = &Cm[(size_t)(rb + r0 + i) * ldc + cbb + c0];
      *(f4*)cp = s0;
      *(f4*)(cp + 4) = s1;
    }
  }
}

// ---------------- bias5[c] = sum_j g[j] * W5[192+j][c] ----------------
__global__ void bias5_kernel(const unsigned* __restrict__ gmax, const float* __restrict__ W5,
                             float* __restrict__ bias5) {
  __shared__ float gs[1024];
  __shared__ float pm[4 * 256];
  int t = threadIdx.x;  // 1024 threads
  gs[t] = fdec(gmax[t]);
  __syncthreads();
  int c = t & 255, p = t >> 8;
  float acc = 0.f;
  for (int j = p * 256; j < p * 256 + 256; ++j)
    acc = fmaf(gs[j], W5[(size_t)(192 + j) * 256 + c], acc);
  pm[p * 256 + c] = acc;
  __syncthreads();
  if (t < 256) bias5[t] = pm[t] + pm[256 + t] + pm[512 + t] + pm[768 + t];
}

// ---------------- final [N,128]@[128,3] + prelu + hidden passthrough ----------------
__global__ __launch_bounds__(256, 2)
void w8_kernel(const float* __restrict__ A, const float* __restrict__ W8,
               const float* __restrict__ pptr, const float* __restrict__ hidden,
               float* __restrict__ out) {
  __shared__ __align__(16) float As[64 * 132];
  __shared__ float W8s[128 * COUT];
  int t = threadIdx.x;
  int rb = blockIdx.x * 64;
  for (int idx = t; idx < 128 * COUT; idx += 256) W8s[idx] = W8[idx];
  for (int idx = t; idx < 64 * 32; idx += 256) {
    int r = idx >> 5, c4 = idx & 31;
    *(f4*)&As[r * 132 + c4 * 4] = *(const f4*)&A[(size_t)(rb + r) * 128 + c4 * 4];
  }
  const float a = *pptr;
  __syncthreads();
  int r = t >> 2, c = t & 3;
  if (c < COUT) {
    float acc = 0.f;
#pragma unroll 8
    for (int j = 0; j < 128; ++j)
      acc = fmaf(As[r * 132 + j], W8s[j * COUT + c], acc);
    float v = fmaxf(acc, 0.f) + a * fminf(acc, 0.f);
    out[(size_t)(rb + r) * COUT + c] = v;
  }
  if (blockIdx.x == 0 && t == 0) out[(size_t)NPTS * COUT] = hidden[0];
}

// ---------------- host launch ----------------
extern "C" void kernel_launch(void* const* d_in, const int* in_sizes, int n_in,
                              void* d_out, int out_size, void* d_ws, size_t ws_size,
                              hipStream_t stream) {
  (void)in_sizes; (void)n_in; (void)out_size; (void)ws_size;
  const float* x      = (const float*)d_in[0];
  const float* hidden = (const float*)d_in[1];
  const float* W1a = (const float*)d_in[2];
  const float* p1a = (const float*)d_in[3];
  const float* W1b = (const float*)d_in[4];
  const float* p1b = (const float*)d_in[5];
  const float* W2a = (const float*)d_in[6];
  const float* p2a = (const float*)d_in[7];
  const float* W2b = (const float*)d_in[8];
  const float* p2b = (const float*)d_in[9];
  const float* W3  = (const float*)d_in[10];
  const float* p3  = (const float*)d_in[11];
  const float* W4  = (const float*)d_in[12];
  const float* p4  = (const float*)d_in[13];
  const float* W5  = (const float*)d_in[14];
  const float* p5  = (const float*)d_in[15];
  const float* W6  = (const float*)d_in[16];
  const float* p6  = (const float*)d_in[17];
  const float* W7  = (const float*)d_in[18];
  const float* p7  = (const float*)d_in[19];
  const float* W8  = (const float*)d_in[20];
  const float* p8  = (const float*)d_in[21];
  float* out = (float*)d_out;

  char* ws = (char*)d_ws;
  size_t off = 0;
  auto carve = [&](size_t bytes) -> void* {
    void* p = ws + off;
    off = (off + bytes + 255) & ~(size_t)255;
    return p;
  };
  float*    x4    = (float*)   carve((size_t)NPTS * 192 * 4);  // [x1|x2|x3], ld=192 (reused as h7)
  float*    vn    = (float*)   carve((size_t)NPTS * 4);
  float*    sn    = (float*)   carve((size_t)NPTS * 4);
  int*      ind   = (int*)     carve((size_t)NPTS * KK * 4);
  float*    T     = (float*)   carve((size_t)NPTS * 4);
  unsigned* cnt   = (unsigned*)carve((size_t)NPTS * 4);
  unsigned* redoCnt = (unsigned*)carve(256);
  int*      redoList = (int*)  carve((size_t)NPTS * 4);
  float*    rpd   = (float*)   carve((size_t)RQSLOTS * 32 * KK * 4);  // redo pass1 lists
  int*      rpi   = (int*)     carve((size_t)RQSLOTS * 32 * KK * 4);
  float*    meanb = (float*)   carve(64 * 4);
  float*    Xc    = (float*)   carve((size_t)NPTS * 64 * 4);   // centered fp32 slice
  short*    Xbf   = (short*)   carve((size_t)NPTS * 64 * 2);   // centered bf16 slice
  float*    plist = (float*)   carve((size_t)2 * NPTS * 64 * 4); // sampler lists; reused as UB
  short*    Ahi   = (short*)   carve((size_t)NPTS * 192 * 2);  // x4 split hi
  short*    Alo   = (short*)   carve((size_t)NPTS * 192 * 2);  // x4 split lo
  short*    Wt4h  = (short*)   carve((size_t)1024 * 192 * 2);
  short*    Wt4l  = (short*)   carve((size_t)1024 * 192 * 2);
  short*    Wt5h  = (short*)   carve((size_t)256 * 192 * 2);
  short*    Wt5l  = (short*)   carve((size_t)256 * 192 * 2);
  unsigned* gmax  = (unsigned*)carve(1024 * 4);
  float*    bias5 = (float*)   carve(256 * 4);
  float*    h5    = (float*)   carve((size_t)NPTS * 256 * 4);  // aliased: survd (knn phase)
  float*    h6    = (float*)   carve((size_t)NPTS * 256 * 4);  // aliased: survi (knn phase)
  float* survd = h5;
  int*   survi = (int*)h6;
  float* h7 = x4;   // x4 dead after W5 GEMM
  float* UB = plist; // plist dead after mergeT; UB = [N][128] (U|B), same size

  // ---- stage 1: knn(x, C=3, reg-query filter) + edgeconv1 -> x4[:, 0:64] ----
  norms_kernel<3><<<64, 256, 0, stream>>>(x, 3, vn);
  sampleTv4_kernel<3><<<dim3(256, 2), 256, 0, stream>>>(x, vn, plist);
  mergeT_kernel<<<64, 256, 0, stream>>>(plist, T, cnt, redoCnt);
  knn_filter3_kernel<<<dim3(128, 8), 256, 0, stream>>>(x, vn, T, survd, survi, cnt);
  select_kernel<<<256, 64, 0, stream>>>(survd, survi, cnt, ind, redoCnt, redoList);
  knn_redo_p1<3><<<RQSLOTS * 32, 256, 0, stream>>>(x, 3, vn, redoList, redoCnt, rpd, rpi);
  knn_redo_p2<<<1, 256, 0, stream>>>(redoList, redoCnt, rpd, rpi, ind);
  knn_redo_kernel<3><<<256, 256, 0, stream>>>(x, 3, vn, redoList, redoCnt, ind, RQSLOTS);
  ub_kernel<3><<<512, 256, 0, stream>>>(x, 3, W1a, UB);
  edgeconv2_kernel<<<4096, 256, 0, stream>>>(UB, ind, W1b, p1a, p1b, x4 + 0, 192);

  // ---- stage 2: knn(x1 centered, MFMA filter) + edgeconv2 -> x4[:, 64:128] ----
  mean64_kernel<<<64, 256, 0, stream>>>(x4 + 0, 192, meanb);
  xc_kernel<<<512, 256, 0, stream>>>(x4 + 0, 192, meanb, Xc, Xbf, vn, sn);
  sampleTv4_kernel<64><<<dim3(256, 2), 256, 0, stream>>>(Xc, vn, plist);
  mergeT_kernel<<<64, 256, 0, stream>>>(plist, T, cnt, redoCnt);
  knn_filter64_mfma<<<dim3(128, 128), 256, 0, stream>>>(Xbf, vn, sn, T, survi, cnt);
  exact_kernel<64><<<NPTS, 256, 0, stream>>>(Xc, 64, vn, cnt, survi, survd);
  select_kernel<<<256, 64, 0, stream>>>(survd, survi, cnt, ind, redoCnt, redoList);
  knn_redo_p1<64><<<RQSLOTS * 32, 256, 0, stream>>>(Xc, 64, vn, redoList, redoCnt, rpd, rpi);
  knn_redo_p2<<<1, 256, 0, stream>>>(redoList, redoCnt, rpd, rpi, ind);
  knn_redo_kernel<64><<<256, 256, 0, stream>>>(Xc, 64, vn, redoList, redoCnt, ind, RQSLOTS);
  ub_kernel<64><<<512, 256, 0, stream>>>(x4 + 0, 192, W2a, UB);
  edgeconv2_kernel<<<4096, 256, 0, stream>>>(UB, ind, W2b, p2a, p2b, x4 + 64, 192);

  // ---- stage 3: knn(x2 centered, MFMA filter) + edgeconv3 -> x4[:, 128:192] ----
  mean64_kernel<<<64, 256, 0, stream>>>(x4 + 64, 192, meanb);
  xc_kernel<<<512, 256, 0, stream>>>(x4 + 64, 192, meanb, Xc, Xbf, vn, sn);
  sampleTv4_kernel<64><<<dim3(256, 2), 256, 0, stream>>>(Xc, vn, plist);
  mergeT_kernel<<<64, 256, 0, stream>>>(plist, T, cnt, redoCnt);
  knn_filter64_mfma<<<dim3(128, 128), 256, 0, stream>>>(Xbf, vn, sn, T, survi, cnt);
  exact_kernel<64><<<NPTS, 256, 0, stream>>>(Xc, 64, vn, cnt, survi, survd);
  select_kernel<<<256, 64, 0, stream>>>(survd, survi, cnt, ind, redoCnt, redoList);
  knn_redo_p1<64><<<RQSLOTS * 32, 256, 0, stream>>>(Xc, 64, vn, redoList, redoCnt, rpd, rpi);
  knn_redo_p2<<<1, 256, 0, stream>>>(redoList, redoCnt, rpd, rpi, ind);
  knn_redo_kernel<64><<<256, 256, 0, stream>>>(Xc, 64, vn, redoList, redoCnt, ind, RQSLOTS);
  ub_kernel<64><<<512, 256, 0, stream>>>(x4 + 64, 192, W3, UB);
  edgeconv1_kernel<<<4096, 256, 0, stream>>>(UB, ind, p3, x4 + 128, 192);

  // ---- split x4 / W4 / W5 into bf16 hi+lo for MFMA tail ----
  splitA_kernel<<<(NPTS * 192 / 8 + 255) / 256, 256, 0, stream>>>(x4, NPTS * 192 / 8, Ahi, Alo);
  splitWt_kernel<<<(1024 * 24 + 255) / 256, 256, 0, stream>>>(W4, 1024, 1024, 192, Wt4h, Wt4l);
  splitWt_kernel<<<(256 * 24 + 255) / 256, 256, 0, stream>>>(W5, 256, 256, 192, Wt5h, Wt5l);

  // ---- x5 = prelu(x4@W4); g = colmax(x5)  [split-bf16 MFMA] ----
  initg_kernel<<<4, 256, 0, stream>>>(gmax);
  gemm_mfma_kernel<1, 192><<<dim3(128, 8), 256, 0, stream>>>(Ahi, Alo, Wt4h, Wt4l, nullptr, p4, nullptr, 0, gmax);

  // ---- bias5 = g @ W5[192:1216] ----
  bias5_kernel<<<1, 1024, 0, stream>>>(gmax, W5, bias5);

  // ---- h5 = prelu(x4@W5[0:192] + bias5)  [split-bf16 MFMA] ----
  gemm_mfma_kernel<2, 192><<<dim3(128, 2), 256, 0, stream>>>(Ahi, Alo, Wt5h, Wt5l, bias5, p5, h5, 256, nullptr);
  // ---- h6 = prelu(h5@W6) ----
  gemm_kernel<0><<<dim3(128, 2), 256, 0, stream>>>(h5, 256, W6, 256, nullptr, p6, h6, 256, 256, nullptr);
  // ---- h7 = prelu(h6@W7) ----
  gemm_kernel<0><<<dim3(128, 1), 256, 0, stream>>>(h6, 256, W7, 128, nullptr, p7, h7, 128, 256, nullptr);
  // ---- out = prelu(h7@W8); out[N*3] = hidden ----
  w8_kernel<<<256, 256, 0, stream>>>(h7, W8, p8, hidden, out);
}